// Round 8
// baseline (453.894 us; speedup 1.0000x reference)
//
#include <hip/hip_runtime.h>
#include <hip/hip_bf16.h>
#include <math.h>

// Problem constants
#define NTOK 32768      // B*L = 64*512
#define Hdim 256
#define Ldim 512
#define Bdim 64
#define NHEAD 4
#define HD 64
#define PADV 49999      // ITEMNUM-1

typedef __bf16 bf16x8 __attribute__((ext_vector_type(8)));
typedef float  f32x4  __attribute__((ext_vector_type(4)));

__device__ __forceinline__ unsigned short f2bf(float f) {
    unsigned int u = __float_as_uint(f);
    unsigned int r = (u + 0x7fffu + ((u >> 16) & 1u)) >> 16;
    return (unsigned short)r;
}
__device__ __forceinline__ float bf2f(unsigned short u) {
    return __uint_as_float(((unsigned int)u) << 16);
}

// async global->LDS, 16B per lane (dest must be wave-uniform base + lane*16)
__device__ __forceinline__ void gload16(const void* g, void* l) {
    __builtin_amdgcn_global_load_lds((const __attribute__((address_space(1))) unsigned int*)g,
                                     (__attribute__((address_space(3))) unsigned int*)l,
                                     16, 0, 0);
}

// ---------------- weight cast: 5 matrices x (2*256*256) f32 -> bf16 ----------------
__global__ __launch_bounds__(256)
void castw_kernel(const float* __restrict__ q, const float* __restrict__ k,
                  const float* __restrict__ v, const float* __restrict__ c1,
                  const float* __restrict__ c2, unsigned short* __restrict__ dst) {
    const float* srcs[5] = {q, k, v, c1, c2};
    const float* s = srcs[blockIdx.y];
    int idx = blockIdx.x * 1024 + threadIdx.x * 4;
    float4 f = *(const float4*)(s + idx);
    unsigned short* d = dst + (size_t)blockIdx.y * 131072 + idx;
    d[0] = f2bf(f.x); d[1] = f2bf(f.y); d[2] = f2bf(f.z); d[3] = f2bf(f.w);
}

// ---------------- prep + ln_attn[0] fused (wave per token), all-bf16 outputs ----------------
__global__ __launch_bounds__(256)
void prep_ln_kernel(const int* __restrict__ seqs_data, const float* __restrict__ seqs,
                    const int* __restrict__ position, const float* __restrict__ time_emb,
                    const float* __restrict__ pos_table, const float* __restrict__ gate_W,
                    const float* __restrict__ gate_b,
                    const float* __restrict__ lnG, const float* __restrict__ lnB,
                    unsigned short* __restrict__ Tbf,
                    unsigned short* __restrict__ QXbf,
                    unsigned short* __restrict__ VINbf,
                    float* __restrict__ gates, float* __restrict__ keepv) {
    int tok  = blockIdx.x * 4 + (threadIdx.x >> 6);
    int lane = threadIdx.x & 63;
    size_t off = (size_t)tok * Hdim + lane * 4;
    int pos = position[tok];
    float4 pe = *(const float4*)(pos_table + (size_t)pos * Hdim + lane * 4);
    float4 sq = *(const float4*)(seqs + off);
    float4 tm = *(const float4*)(time_emb + off);
    float keep = (seqs_data[tok] != PADV) ? 1.0f : 0.0f;
    float4 t = {tm.x + pe.x, tm.y + pe.y, tm.z + pe.z, tm.w + pe.w};
    float4 s = {(sq.x + pe.x) * keep, (sq.y + pe.y) * keep,
                (sq.z + pe.z) * keep, (sq.w + pe.w) * keep};
    ushort4 tb = {f2bf(t.x), f2bf(t.y), f2bf(t.z), f2bf(t.w)};
    *(ushort4*)(Tbf + off) = tb;
    float4 gw0 = *(const float4*)(gate_W + lane * 4);
    float4 gw1 = *(const float4*)(gate_W + Hdim + lane * 4);
    float r0 = s.x + s.y + s.z + s.w;
    float r1 = s.x * s.x + s.y * s.y + s.z * s.z + s.w * s.w;
    float r2 = t.x * gw0.x + t.y * gw0.y + t.z * gw0.z + t.w * gw0.w;
    float r3 = t.x * gw1.x + t.y * gw1.y + t.z * gw1.z + t.w * gw1.w;
#pragma unroll
    for (int o = 1; o < 64; o <<= 1) {
        r0 += __shfl_xor(r0, o, 64);
        r1 += __shfl_xor(r1, o, 64);
        r2 += __shfl_xor(r2, o, 64);
        r3 += __shfl_xor(r3, o, 64);
    }
    float mean = r0 * (1.0f / Hdim);
    float var  = fmaxf(r1 * (1.0f / Hdim) - mean * mean, 0.0f);
    float rstd = rsqrtf(var + 1e-8f);
    if (lane == 0) {
        gates[(size_t)tok * 2 + 0] = 1.0f / (1.0f + __expf(-(r2 + gate_b[0])));
        gates[(size_t)tok * 2 + 1] = 1.0f / (1.0f + __expf(-(r3 + gate_b[1])));
        keepv[tok] = keep;
    }
    float4 g4 = *(const float4*)(lnG + lane * 4);
    float4 b4 = *(const float4*)(lnB + lane * 4);
    float4 y = {(s.x - mean) * rstd * g4.x + b4.x, (s.y - mean) * rstd * g4.y + b4.y,
                (s.z - mean) * rstd * g4.z + b4.z, (s.w - mean) * rstd * g4.w + b4.w};
    ushort4 yb = {f2bf(y.x), f2bf(y.y), f2bf(y.z), f2bf(y.w)};
    *(ushort4*)(QXbf + off) = yb;
    ushort4 vb = {f2bf(s.x + t.x), f2bf(s.y + t.y), f2bf(s.z + t.z), f2bf(s.w + t.w)};
    *(ushort4*)(VINbf + off) = vb;
}

// ---------------- ln_ffn: x = Q(bf16) + QA(bf16); LN -> QXbf in place ----------------
__global__ __launch_bounds__(256)
void ln2_kernel(unsigned short* QXbf, const unsigned short* __restrict__ QA,
                const float* __restrict__ lnG, const float* __restrict__ lnB) {
    int tok  = blockIdx.x * 4 + (threadIdx.x >> 6);
    int lane = threadIdx.x & 63;
    size_t off = (size_t)tok * Hdim + lane * 4;
    ushort4 q = *(const ushort4*)(QXbf + off);
    ushort4 a = *(const ushort4*)(QA + off);
    float4 x = {bf2f(q.x) + bf2f(a.x), bf2f(q.y) + bf2f(a.y),
                bf2f(q.z) + bf2f(a.z), bf2f(q.w) + bf2f(a.w)};
    float r0 = x.x + x.y + x.z + x.w;
    float r1 = x.x * x.x + x.y * x.y + x.z * x.z + x.w * x.w;
#pragma unroll
    for (int o = 1; o < 64; o <<= 1) {
        r0 += __shfl_xor(r0, o, 64);
        r1 += __shfl_xor(r1, o, 64);
    }
    float mean = r0 * (1.0f / Hdim);
    float var  = fmaxf(r1 * (1.0f / Hdim) - mean * mean, 0.0f);
    float rstd = rsqrtf(var + 1e-8f);
    float4 g4 = *(const float4*)(lnG + lane * 4);
    float4 b4 = *(const float4*)(lnB + lane * 4);
    ushort4 yb = {f2bf((x.x - mean) * rstd * g4.x + b4.x),
                  f2bf((x.y - mean) * rstd * g4.y + b4.y),
                  f2bf((x.z - mean) * rstd * g4.z + b4.z),
                  f2bf((x.w - mean) * rstd * g4.w + b4.w)};
    *(ushort4*)(QXbf + off) = yb;
}

// ---------------- merged q/k/v GEMM, 128x256 full-N tile ----------------
// grid (NTOK/128, 3); z=0: Q; z=1: K; z=2: V -> VT (two-pass LDS transpose)
__global__ __launch_bounds__(256, 1)
void gemm_qkv_kernel(const unsigned short* __restrict__ QXbf,
                     const unsigned short* __restrict__ Tbf,
                     const unsigned short* __restrict__ VINbf,
                     const unsigned short* __restrict__ qW,
                     const unsigned short* __restrict__ kW,
                     const unsigned short* __restrict__ vW,
                     const float* __restrict__ qb, const float* __restrict__ kb,
                     const float* __restrict__ vb,
                     unsigned short* __restrict__ Qbf,
                     unsigned short* __restrict__ Kbf,
                     unsigned short* __restrict__ VT) {
    // As(8K)+Ws(16K) = 24K, union with Ct[128][136] = 34.8K
    __shared__ __align__(16) char smem[128 * 136 * 2];
    __bf16 (*As)[32]  = (__bf16 (*)[32])smem;
    __bf16 (*Ws)[32]  = (__bf16 (*)[32])(smem + 8192);
    __bf16 (*Ct)[136] = (__bf16 (*)[136])smem;
    int z = blockIdx.y;
    const unsigned short* A = (z == 0) ? QXbf : (z == 1) ? Tbf : VINbf;
    const unsigned short* W = (z == 0) ? qW : (z == 1) ? kW : vW;
    const float* bias       = (z == 0) ? qb : (z == 1) ? kb : vb;

    int tid = threadIdx.x, lane = tid & 63, w = tid >> 6;
    int wr = w & 1, wc = w >> 1;           // wave: rows wr*64.., cols wc*128..
    int m0 = blockIdx.x * 128;
    f32x4 acc[4][8];
#pragma unroll
    for (int i = 0; i < 4; ++i)
#pragma unroll
        for (int j = 0; j < 8; ++j) acc[i][j] = (f32x4)(0.0f);
    int mrow = lane & 15, kq = (lane >> 4) * 8;
    for (int kc = 0; kc < Hdim; kc += 32) {
        __syncthreads();
        {
            int c0 = tid, c1 = tid + 256;
            gload16(A + (size_t)(m0 + (c0 >> 2)) * Hdim + kc + (c0 & 3) * 8, (__bf16*)As + c0 * 8);
            gload16(A + (size_t)(m0 + (c1 >> 2)) * Hdim + kc + (c1 & 3) * 8, (__bf16*)As + c1 * 8);
#pragma unroll
            for (int it = 0; it < 4; ++it) {
                int c = tid + it * 256;
                gload16(W + (size_t)(c >> 2) * Hdim + kc + (c & 3) * 8, (__bf16*)Ws + c * 8);
            }
        }
        __syncthreads();
        bf16x8 af[4], bfr[8];
#pragma unroll
        for (int i = 0; i < 4; ++i)
            af[i] = *(const bf16x8*)&As[wr * 64 + i * 16 + mrow][kq];
#pragma unroll
        for (int j = 0; j < 8; ++j)
            bfr[j] = *(const bf16x8*)&Ws[wc * 128 + j * 16 + mrow][kq];
#pragma unroll
        for (int i = 0; i < 4; ++i)
#pragma unroll
            for (int j = 0; j < 8; ++j)
                acc[i][j] = __builtin_amdgcn_mfma_f32_16x16x32_bf16(af[i], bfr[j], acc[i][j], 0, 0, 0);
    }
    int colq = lane & 15, rowq = (lane >> 4) * 4;
    if (z < 2) {
        unsigned short* outBF = (z == 0) ? Qbf : Kbf;
#pragma unroll
        for (int i = 0; i < 4; ++i)
#pragma unroll
            for (int r = 0; r < 4; ++r) {
                int m = m0 + wr * 64 + i * 16 + rowq + r;
#pragma unroll
                for (int j = 0; j < 8; ++j) {
                    int n = wc * 128 + j * 16 + colq;
                    outBF[(size_t)m * Hdim + n] = f2bf(acc[i][j][r] + bias[n]);
                }
            }
    } else {
        int bb = m0 >> 9, l0 = m0 & 511;
#pragma unroll
        for (int p = 0; p < 2; ++p) {
            __syncthreads();   // frag reads (p=0) / prev copy (p=1) done
            if (wc == p) {
#pragma unroll
                for (int i = 0; i < 4; ++i)
#pragma unroll
                    for (int r = 0; r < 4; ++r) {
                        int ml = wr * 64 + i * 16 + rowq + r;
#pragma unroll
                        for (int j = 0; j < 8; ++j) {
                            int cl = j * 16 + colq;
                            Ct[cl][ml] = (__bf16)(acc[i][j][r] + bias[p * 128 + cl]);
                        }
                    }
            }
            __syncthreads();
#pragma unroll
            for (int it = 0; it < 8; ++it) {
                int c = tid + it * 256;
                int nl = c >> 4, o8 = (c & 15) * 8;
                int n = p * 128 + nl;
                int hh = n >> 6, dd = n & 63;
                *(bf16x8*)(VT + ((((size_t)bb * NHEAD + hh) * HD + dd) * Ldim + l0 + o8)) =
                    *(const bf16x8*)&Ct[nl][o8];
            }
        }
    }
}

// ---------------- c1 GEMM 128x256 full-N: HID = relu(Y@c1W^T + b) ----------------
__global__ __launch_bounds__(256, 1)
void gemm_c1_kernel(const unsigned short* __restrict__ A,
                    const unsigned short* __restrict__ W,
                    const float* __restrict__ bias,
                    unsigned short* __restrict__ outBF) {
    __shared__ __bf16 As[128][32];
    __shared__ __bf16 Ws[256][32];
    int tid = threadIdx.x, lane = tid & 63, w = tid >> 6;
    int wr = w & 1, wc = w >> 1;
    int m0 = blockIdx.x * 128;
    f32x4 acc[4][8];
#pragma unroll
    for (int i = 0; i < 4; ++i)
#pragma unroll
        for (int j = 0; j < 8; ++j) acc[i][j] = (f32x4)(0.0f);
    int mrow = lane & 15, kq = (lane >> 4) * 8;
    for (int kc = 0; kc < Hdim; kc += 32) {
        __syncthreads();
        {
            int c0 = tid, c1 = tid + 256;
            gload16(A + (size_t)(m0 + (c0 >> 2)) * Hdim + kc + (c0 & 3) * 8, (__bf16*)As + c0 * 8);
            gload16(A + (size_t)(m0 + (c1 >> 2)) * Hdim + kc + (c1 & 3) * 8, (__bf16*)As + c1 * 8);
#pragma unroll
            for (int it = 0; it < 4; ++it) {
                int c = tid + it * 256;
                gload16(W + (size_t)(c >> 2) * Hdim + kc + (c & 3) * 8, (__bf16*)Ws + c * 8);
            }
        }
        __syncthreads();
        bf16x8 af[4], bfr[8];
#pragma unroll
        for (int i = 0; i < 4; ++i)
            af[i] = *(const bf16x8*)&As[wr * 64 + i * 16 + mrow][kq];
#pragma unroll
        for (int j = 0; j < 8; ++j)
            bfr[j] = *(const bf16x8*)&Ws[wc * 128 + j * 16 + mrow][kq];
#pragma unroll
        for (int i = 0; i < 4; ++i)
#pragma unroll
            for (int j = 0; j < 8; ++j)
                acc[i][j] = __builtin_amdgcn_mfma_f32_16x16x32_bf16(af[i], bfr[j], acc[i][j], 0, 0, 0);
    }
    int colq = lane & 15, rowq = (lane >> 4) * 4;
#pragma unroll
    for (int i = 0; i < 4; ++i)
#pragma unroll
        for (int r = 0; r < 4; ++r) {
            int m = m0 + wr * 64 + i * 16 + rowq + r;
#pragma unroll
            for (int j = 0; j < 8; ++j) {
                int n = wc * 128 + j * 16 + colq;
                outBF[(size_t)m * Hdim + n] = f2bf(fmaxf(acc[i][j][r] + bias[n], 0.0f));
            }
        }
}

// ---------------- c2 GEMM 64x256 + bf16 resid (LDS-prefetched) + keep + row-LN ----------------
__global__ __launch_bounds__(256)
void gemm_c2ln_kernel(const unsigned short* __restrict__ A,     // hidden bf16
                      const unsigned short* __restrict__ W,     // c2W bf16
                      const float* __restrict__ bias,
                      const unsigned short* __restrict__ Ybf,   // resid bf16 (= QXbf)
                      const float* __restrict__ keepv,
                      const float* __restrict__ lnG, const float* __restrict__ lnB,
                      const unsigned short* __restrict__ Tbf,   // nullable (for VIN)
                      float* outF,                              // d_out (i=1) or null
                      unsigned short* __restrict__ outQ,        // next-Q bf16 (i=0) or null
                      unsigned short* __restrict__ outVIN) {    // next-VIN bf16 (i=0) or null
    __shared__ __bf16 As[64][32];      // 4 KB
    __shared__ __bf16 Ws[256][32];     // 16 KB
    __shared__ __bf16 Rs[64][256];     // 32 KB resid tile
    __shared__ float red[4][64][2];    // 2 KB
    int tid = threadIdx.x, lane = tid & 63, w = tid >> 6;
    int colq = lane & 15, grp = lane >> 4, rowq = grp * 4, kq = grp * 8;
    int m0 = blockIdx.x * 64;
    // prefetch resid tile (64x256 bf16 = 2048 chunks of 16B)
#pragma unroll
    for (int it = 0; it < 8; ++it) {
        int c = tid + it * 256;
        gload16(Ybf + (size_t)(m0 + (c >> 5)) * Hdim + (c & 31) * 8, (__bf16*)Rs + c * 8);
    }
    f32x4 acc[4][4];
#pragma unroll
    for (int i = 0; i < 4; ++i)
#pragma unroll
        for (int j = 0; j < 4; ++j) acc[i][j] = (f32x4)(0.0f);
    for (int kc = 0; kc < Hdim; kc += 32) {
        __syncthreads();
        gload16(A + (size_t)(m0 + (tid >> 2)) * Hdim + kc + (tid & 3) * 8,
                (__bf16*)As + tid * 8);
#pragma unroll
        for (int it = 0; it < 4; ++it) {
            int c = tid + it * 256;
            gload16(W + (size_t)(c >> 2) * Hdim + kc + (c & 3) * 8, (__bf16*)Ws + c * 8);
        }
        __syncthreads();
        bf16x8 af[4], bfr[4];
#pragma unroll
        for (int i = 0; i < 4; ++i)
            af[i] = *(const bf16x8*)&As[i * 16 + colq][kq];
#pragma unroll
        for (int j = 0; j < 4; ++j)
            bfr[j] = *(const bf16x8*)&Ws[w * 64 + j * 16 + colq][kq];
#pragma unroll
        for (int i = 0; i < 4; ++i)
#pragma unroll
            for (int j = 0; j < 4; ++j)
                acc[i][j] = __builtin_amdgcn_mfma_f32_16x16x32_bf16(af[i], bfr[j], acc[i][j], 0, 0, 0);
    }
    // S_new = (acc + bias + resid) * keep
#pragma unroll
    for (int i = 0; i < 4; ++i)
#pragma unroll
        for (int r = 0; r < 4; ++r) {
            int m = m0 + i * 16 + rowq + r;
            float kf = keepv[m];
#pragma unroll
            for (int j = 0; j < 4; ++j) {
                int nl = w * 64 + j * 16 + colq;
                float v = acc[i][j][r] + bias[nl] + bf2f(((unsigned short*)Rs)[(i * 16 + rowq + r) * 256 + nl]);
                acc[i][j][r] = v * kf;
            }
        }
    // row stats
#pragma unroll
    for (int i = 0; i < 4; ++i)
#pragma unroll
        for (int r = 0; r < 4; ++r) {
            float s1 = acc[i][0][r] + acc[i][1][r] + acc[i][2][r] + acc[i][3][r];
            float s2 = acc[i][0][r] * acc[i][0][r] + acc[i][1][r] * acc[i][1][r] +
                       acc[i][2][r] * acc[i][2][r] + acc[i][3][r] * acc[i][3][r];
#pragma unroll
            for (int o = 1; o < 16; o <<= 1) {
                s1 += __shfl_xor(s1, o, 64);
                s2 += __shfl_xor(s2, o, 64);
            }
            if (colq == 0) {
                red[w][i * 16 + rowq + r][0] = s1;
                red[w][i * 16 + rowq + r][1] = s2;
            }
        }
    __syncthreads();
    float mean_[4][4], rstd_[4][4];
#pragma unroll
    for (int i = 0; i < 4; ++i)
#pragma unroll
        for (int r = 0; r < 4; ++r) {
            int row = i * 16 + rowq + r;
            float s1 = red[0][row][0] + red[1][row][0] + red[2][row][0] + red[3][row][0];
            float s2 = red[0][row][1] + red[1][row][1] + red[2][row][1] + red[3][row][1];
            float mean = s1 * (1.0f / Hdim);
            float var  = fmaxf(s2 * (1.0f / Hdim) - mean * mean, 0.0f);
            mean_[i][r] = mean;
            rstd_[i][r] = rsqrtf(var + 1e-8f);
        }
#pragma unroll
    for (int i = 0; i < 4; ++i)
#pragma unroll
        for (int r = 0; r < 4; ++r) {
            int m = m0 + i * 16 + rowq + r;
#pragma unroll
            for (int j = 0; j < 4; ++j) {
                int nl = w * 64 + j * 16 + colq;
                float v = acc[i][j][r];
                float y = (v - mean_[i][r]) * rstd_[i][r] * lnG[nl] + lnB[nl];
                if (outF)   outF[(size_t)m * Hdim + nl] = y;
                if (outQ)   outQ[(size_t)m * Hdim + nl] = f2bf(y);
                if (outVIN) outVIN[(size_t)m * Hdim + nl] =
                    f2bf(v + bf2f(Tbf[(size_t)m * Hdim + nl]));
            }
        }
}

// ---------------- persistent per-(b,h) gated causal flash attention ----------------
#define AK_STRIDE 72
#define AV_STRIDE 520
#define ATTN_LDS (512 * AK_STRIDE * 2 + 64 * AV_STRIDE * 2 + 128 * AK_STRIDE * 2)
__global__ __launch_bounds__(512, 1)
void attn_mfma_kernel(const unsigned short* __restrict__ Qg,
                      const unsigned short* __restrict__ Kg,
                      const unsigned short* __restrict__ VTg,
                      const float* __restrict__ gates,
                      unsigned short* __restrict__ Ob, int blk) {
    extern __shared__ __align__(16) char smem[];
    __bf16 (*Ks)[AK_STRIDE]  = (__bf16 (*)[AK_STRIDE])smem;
    __bf16 (*VTs)[AV_STRIDE] = (__bf16 (*)[AV_STRIDE])(smem + 512 * AK_STRIDE * 2);
    __bf16 (*QPs)[AK_STRIDE] = (__bf16 (*)[AK_STRIDE])(smem + 512 * AK_STRIDE * 2 + 64 * AV_STRIDE * 2);
    int h = blockIdx.x & 3, b = blockIdx.x >> 2;
    int tid = threadIdx.x, lane = tid & 63, w = tid >> 6;
    int colq = lane & 15, grp = lane >> 4;
    int rowq = grp * 4, kq = grp * 8;

    size_t baseK = (size_t)b * Ldim * Hdim + h * HD;
#pragma unroll
    for (int it = 0; it < 8; ++it) {
        int c = tid + it * 512;
        int r = c >> 3, o = (c & 7) * 8;
        *(bf16x8*)&Ks[r][o] = *(const bf16x8*)(Kg + baseK + (size_t)r * Hdim + o);
    }
    size_t baseV = ((size_t)b * NHEAD + h) * HD * Ldim;
#pragma unroll
    for (int it = 0; it < 8; ++it) {
        int c = tid + it * 512;
        int d = c >> 6, k = (c & 63) * 8;
        *(bf16x8*)&VTs[d][k] = *(const bf16x8*)(VTg + baseV + (size_t)d * Ldim + k);
    }

    const float lscale = 0.125f * 1.44269504f;
    for (int qt = 0; qt < 4; ++qt) {
        int q0 = qt * 128;
        __syncthreads();
#pragma unroll
        for (int it = 0; it < 2; ++it) {
            int c = tid + it * 512;
            int r = c >> 3, o = (c & 7) * 8;
            *(bf16x8*)&QPs[r][o] =
                *(const bf16x8*)(Qg + (size_t)(b * Ldim + q0 + r) * Hdim + h * HD + o);
        }
        float gql[4];
#pragma unroll
        for (int r = 0; r < 4; ++r)
            gql[r] = gates[((size_t)b * Ldim + q0 + w * 16 + rowq + r) * 2 + blk] * lscale;
        __syncthreads();
        bf16x8 afq0 = *(const bf16x8*)&QPs[w * 16 + colq][kq];
        bf16x8 afq1 = *(const bf16x8*)&QPs[w * 16 + colq][32 + kq];

        float lrun[4] = {0.0f, 0.0f, 0.0f, 0.0f};
        f32x4 accO[4];
#pragma unroll
        for (int jd = 0; jd < 4; ++jd) accO[jd] = (f32x4)(0.0f);

        int nkt = 2 * qt + 2;
        for (int kt = 0; kt < nkt; ++kt) {
            int k0 = kt * 64;
            f32x4 s[4];
#pragma unroll
            for (int j = 0; j < 4; ++j) s[j] = (f32x4)(0.0f);
#pragma unroll
            for (int j = 0; j < 4; ++j) {
                bf16x8 bk0 = *(const bf16x8*)&Ks[k0 + j * 16 + colq][kq];
                bf16x8 bk1 = *(const bf16x8*)&Ks[k0 + j * 16 + colq][32 + kq];
                s[j] = __builtin_amdgcn_mfma_f32_16x16x32_bf16(afq0, bk0, s[j], 0, 0, 0);
                s[j] = __builtin_amdgcn_mfma_f32_16x16x32_bf16(afq1, bk1, s[j], 0, 0, 0);
            }
            float gkv[4];
#pragma unroll
            for (int j = 0; j < 4; ++j)
                gkv[j] = gates[((size_t)b * Ldim + k0 + j * 16 + colq) * 2 + blk];
#pragma unroll
            for (int r = 0; r < 4; ++r) {
                int qg = q0 + w * 16 + rowq + r;
                float su = 0.0f;
                float p[4];
#pragma unroll
                for (int j = 0; j < 4; ++j) {
                    int kg = k0 + j * 16 + colq;
                    float v = s[j][r] * gql[r] * gkv[j];
                    v = (kg > qg) ? -1e38f : v;
                    float e = exp2f(v);
                    p[j] = e;
                    su += e;
                }
#pragma unroll
                for (int off = 1; off < 16; off <<= 1)
                    su += __shfl_xor(su, off, 16);
                lrun[r] += su;
#pragma unroll
                for (int j = 0; j < 4; ++j)
                    QPs[w * 16 + rowq + r][j * 16 + colq] = (__bf16)p[j];
            }
            bf16x8 ap0 = *(const bf16x8*)&QPs[w * 16 + colq][kq];
            bf16x8 ap1 = *(const bf16x8*)&QPs[w * 16 + colq][32 + kq];
#pragma unroll
            for (int jd = 0; jd < 4; ++jd) {
                bf16x8 bv0 = *(const bf16x8*)&VTs[jd * 16 + colq][k0 + kq];
                bf16x8 bv1 = *(const bf16x8*)&VTs[jd * 16 + colq][k0 + 32 + kq];
                accO[jd] = __builtin_amdgcn_mfma_f32_16x16x32_bf16(ap0, bv0, accO[jd], 0, 0, 0);
                accO[jd] = __builtin_amdgcn_mfma_f32_16x16x32_bf16(ap1, bv1, accO[jd], 0, 0, 0);
            }
        }
#pragma unroll
        for (int r = 0; r < 4; ++r) {
            float inv = 1.0f / lrun[r];
#pragma unroll
            for (int jd = 0; jd < 4; ++jd)
                Ob[(size_t)(b * Ldim + q0 + w * 16 + rowq + r) * Hdim + h * HD + jd * 16 + colq] =
                    f2bf(accO[jd][r] * inv);
        }
    }
}

// ---------------- launcher ----------------
extern "C" void kernel_launch(void* const* d_in, const int* in_sizes, int n_in,
                              void* d_out, int out_size, void* d_ws, size_t ws_size,
                              hipStream_t stream) {
    const int*   seqs_data = (const int*)d_in[0];
    const float* seqs      = (const float*)d_in[1];
    const int*   position  = (const int*)d_in[2];
    const float* time_emb  = (const float*)d_in[3];
    const float* pos_table = (const float*)d_in[4];
    const float* gate_W    = (const float*)d_in[5];
    const float* gate_b    = (const float*)d_in[6];
    const float* ln_attn_g = (const float*)d_in[7];
    const float* ln_attn_b = (const float*)d_in[8];
    const float* qW        = (const float*)d_in[9];
    const float* qb        = (const float*)d_in[10];
    const float* kW        = (const float*)d_in[11];
    const float* kb        = (const float*)d_in[12];
    const float* vW        = (const float*)d_in[13];
    const float* vb        = (const float*)d_in[14];
    const float* ln_ffn_g  = (const float*)d_in[15];
    const float* ln_ffn_b  = (const float*)d_in[16];
    const float* c1W       = (const float*)d_in[17];
    const float* c1b       = (const float*)d_in[18];
    const float* c2W       = (const float*)d_in[19];
    const float* c2b       = (const float*)d_in[20];
    const float* last_g    = (const float*)d_in[21];
    const float* last_b    = (const float*)d_in[22];

    size_t BUF = (size_t)NTOK * Hdim;
    float* fws = (float*)d_ws;
    float* GATES = fws;                       // NTOK*2
    float* KEEP  = GATES + (size_t)NTOK * 2;  // NTOK
    unsigned short* bws   = (unsigned short*)(KEEP + NTOK);
    unsigned short* Tbf   = bws;
    unsigned short* QXbf  = Tbf + BUF;        // Q / y / next-Q (in place)
    unsigned short* VINbf = QXbf + BUF;
    unsigned short* HIDbf = VINbf + BUF;
    unsigned short* Qbf   = HIDbf + BUF;
    unsigned short* Kbf   = Qbf + BUF;
    unsigned short* VTbf  = Kbf + BUF;        // V^T [B][NH][HD][L]
    unsigned short* QAbf  = VTbf + BUF;
    unsigned short* Wbf   = QAbf + BUF;
    size_t WB = (size_t)Hdim * Hdim;
    unsigned short* qWbf  = Wbf;
    unsigned short* kWbf  = Wbf + 2 * WB;
    unsigned short* vWbf  = Wbf + 4 * WB;
    unsigned short* c1Wbf = Wbf + 6 * WB;
    unsigned short* c2Wbf = Wbf + 8 * WB;

    castw_kernel<<<dim3(128, 5), 256, 0, stream>>>(qW, kW, vW, c1W, c2W, Wbf);
    prep_ln_kernel<<<NTOK / 4, 256, 0, stream>>>(seqs_data, seqs, position, time_emb,
                                                 pos_table, gate_W, gate_b,
                                                 ln_attn_g, ln_attn_b,
                                                 Tbf, QXbf, VINbf, GATES, KEEP);

    dim3 qkvgrid(NTOK / 128, 3);   // (256, 3)
    for (int i = 0; i < 2; ++i) {
        gemm_qkv_kernel<<<qkvgrid, 256, 0, stream>>>(QXbf, Tbf, VINbf,
                                                     qWbf + i * WB, kWbf + i * WB, vWbf + i * WB,
                                                     qb + i * Hdim, kb + i * Hdim, vb + i * Hdim,
                                                     Qbf, Kbf, VTbf);
        attn_mfma_kernel<<<Bdim * NHEAD, 512, ATTN_LDS, stream>>>(Qbf, Kbf, VTbf, GATES, QAbf, i);
        ln2_kernel<<<NTOK / 4, 256, 0, stream>>>(QXbf, QAbf,
                                                 ln_ffn_g + i * Hdim, ln_ffn_b + i * Hdim);
        gemm_c1_kernel<<<NTOK / 128, 256, 0, stream>>>(QXbf, c1Wbf + i * WB, c1b + i * Hdim, HIDbf);
        if (i == 0) {
            gemm_c2ln_kernel<<<NTOK / 64, 256, 0, stream>>>(
                HIDbf, c2Wbf, c2b, QXbf, KEEP,
                ln_attn_g + Hdim, ln_attn_b + Hdim, Tbf,
                nullptr, QXbf, VINbf);
        } else {
            gemm_c2ln_kernel<<<NTOK / 64, 256, 0, stream>>>(
                HIDbf, c2Wbf + WB, c2b + Hdim, QXbf, KEEP,
                last_g, last_b, nullptr,
                (float*)d_out, nullptr, nullptr);
        }
    }
}

// Round 9
// 390.309 us; speedup vs baseline: 1.1629x; 1.1629x over previous
//
#include <hip/hip_runtime.h>
#include <hip/hip_bf16.h>
#include <math.h>

// Problem constants
#define NTOK 32768      // B*L = 64*512
#define Hdim 256
#define Ldim 512
#define Bdim 64
#define NHEAD 4
#define HD 64
#define PADV 49999      // ITEMNUM-1

typedef __bf16 bf16x8 __attribute__((ext_vector_type(8)));
typedef float  f32x4  __attribute__((ext_vector_type(4)));

__device__ __forceinline__ unsigned short f2bf(float f) {
    unsigned int u = __float_as_uint(f);
    unsigned int r = (u + 0x7fffu + ((u >> 16) & 1u)) >> 16;
    return (unsigned short)r;
}
__device__ __forceinline__ float bf2f(unsigned short u) {
    return __uint_as_float(((unsigned int)u) << 16);
}

// async global->LDS, 16B per lane (dest must be wave-uniform base + lane*16)
__device__ __forceinline__ void gload16(const void* g, void* l) {
    __builtin_amdgcn_global_load_lds((const __attribute__((address_space(1))) unsigned int*)g,
                                     (__attribute__((address_space(3))) unsigned int*)l,
                                     16, 0, 0);
}

// ---------------- weight cast: 5 matrices x (2*256*256) f32 -> bf16 ----------------
__global__ __launch_bounds__(256)
void castw_kernel(const float* __restrict__ q, const float* __restrict__ k,
                  const float* __restrict__ v, const float* __restrict__ c1,
                  const float* __restrict__ c2, unsigned short* __restrict__ dst) {
    const float* srcs[5] = {q, k, v, c1, c2};
    const float* s = srcs[blockIdx.y];
    int idx = blockIdx.x * 1024 + threadIdx.x * 4;
    float4 f = *(const float4*)(s + idx);
    unsigned short* d = dst + (size_t)blockIdx.y * 131072 + idx;
    d[0] = f2bf(f.x); d[1] = f2bf(f.y); d[2] = f2bf(f.z); d[3] = f2bf(f.w);
}

// ---------------- prep + ln_attn[0] fused (wave per token), all-bf16 outputs ----------------
__global__ __launch_bounds__(256)
void prep_ln_kernel(const int* __restrict__ seqs_data, const float* __restrict__ seqs,
                    const int* __restrict__ position, const float* __restrict__ time_emb,
                    const float* __restrict__ pos_table, const float* __restrict__ gate_W,
                    const float* __restrict__ gate_b,
                    const float* __restrict__ lnG, const float* __restrict__ lnB,
                    unsigned short* __restrict__ Tbf,
                    unsigned short* __restrict__ QXbf,
                    unsigned short* __restrict__ VINbf,
                    float* __restrict__ gates, float* __restrict__ keepv) {
    int tok  = blockIdx.x * 4 + (threadIdx.x >> 6);
    int lane = threadIdx.x & 63;
    size_t off = (size_t)tok * Hdim + lane * 4;
    int pos = position[tok];
    float4 pe = *(const float4*)(pos_table + (size_t)pos * Hdim + lane * 4);
    float4 sq = *(const float4*)(seqs + off);
    float4 tm = *(const float4*)(time_emb + off);
    float keep = (seqs_data[tok] != PADV) ? 1.0f : 0.0f;
    float4 t = {tm.x + pe.x, tm.y + pe.y, tm.z + pe.z, tm.w + pe.w};
    float4 s = {(sq.x + pe.x) * keep, (sq.y + pe.y) * keep,
                (sq.z + pe.z) * keep, (sq.w + pe.w) * keep};
    ushort4 tb = {f2bf(t.x), f2bf(t.y), f2bf(t.z), f2bf(t.w)};
    *(ushort4*)(Tbf + off) = tb;
    float4 gw0 = *(const float4*)(gate_W + lane * 4);
    float4 gw1 = *(const float4*)(gate_W + Hdim + lane * 4);
    float r0 = s.x + s.y + s.z + s.w;
    float r1 = s.x * s.x + s.y * s.y + s.z * s.z + s.w * s.w;
    float r2 = t.x * gw0.x + t.y * gw0.y + t.z * gw0.z + t.w * gw0.w;
    float r3 = t.x * gw1.x + t.y * gw1.y + t.z * gw1.z + t.w * gw1.w;
#pragma unroll
    for (int o = 1; o < 64; o <<= 1) {
        r0 += __shfl_xor(r0, o, 64);
        r1 += __shfl_xor(r1, o, 64);
        r2 += __shfl_xor(r2, o, 64);
        r3 += __shfl_xor(r3, o, 64);
    }
    float mean = r0 * (1.0f / Hdim);
    float var  = fmaxf(r1 * (1.0f / Hdim) - mean * mean, 0.0f);
    float rstd = rsqrtf(var + 1e-8f);
    if (lane == 0) {
        gates[(size_t)tok * 2 + 0] = 1.0f / (1.0f + __expf(-(r2 + gate_b[0])));
        gates[(size_t)tok * 2 + 1] = 1.0f / (1.0f + __expf(-(r3 + gate_b[1])));
        keepv[tok] = keep;
    }
    float4 g4 = *(const float4*)(lnG + lane * 4);
    float4 b4 = *(const float4*)(lnB + lane * 4);
    float4 y = {(s.x - mean) * rstd * g4.x + b4.x, (s.y - mean) * rstd * g4.y + b4.y,
                (s.z - mean) * rstd * g4.z + b4.z, (s.w - mean) * rstd * g4.w + b4.w};
    ushort4 yb = {f2bf(y.x), f2bf(y.y), f2bf(y.z), f2bf(y.w)};
    *(ushort4*)(QXbf + off) = yb;
    ushort4 vb = {f2bf(s.x + t.x), f2bf(s.y + t.y), f2bf(s.z + t.z), f2bf(s.w + t.w)};
    *(ushort4*)(VINbf + off) = vb;
}

// ---------------- ln_ffn: x = Q(bf16) + QA(bf16); LN -> QXbf in place ----------------
__global__ __launch_bounds__(256)
void ln2_kernel(unsigned short* QXbf, const unsigned short* __restrict__ QA,
                const float* __restrict__ lnG, const float* __restrict__ lnB) {
    int tok  = blockIdx.x * 4 + (threadIdx.x >> 6);
    int lane = threadIdx.x & 63;
    size_t off = (size_t)tok * Hdim + lane * 4;
    ushort4 q = *(const ushort4*)(QXbf + off);
    ushort4 a = *(const ushort4*)(QA + off);
    float4 x = {bf2f(q.x) + bf2f(a.x), bf2f(q.y) + bf2f(a.y),
                bf2f(q.z) + bf2f(a.z), bf2f(q.w) + bf2f(a.w)};
    float r0 = x.x + x.y + x.z + x.w;
    float r1 = x.x * x.x + x.y * x.y + x.z * x.z + x.w * x.w;
#pragma unroll
    for (int o = 1; o < 64; o <<= 1) {
        r0 += __shfl_xor(r0, o, 64);
        r1 += __shfl_xor(r1, o, 64);
    }
    float mean = r0 * (1.0f / Hdim);
    float var  = fmaxf(r1 * (1.0f / Hdim) - mean * mean, 0.0f);
    float rstd = rsqrtf(var + 1e-8f);
    float4 g4 = *(const float4*)(lnG + lane * 4);
    float4 b4 = *(const float4*)(lnB + lane * 4);
    ushort4 yb = {f2bf((x.x - mean) * rstd * g4.x + b4.x),
                  f2bf((x.y - mean) * rstd * g4.y + b4.y),
                  f2bf((x.z - mean) * rstd * g4.z + b4.z),
                  f2bf((x.w - mean) * rstd * g4.w + b4.w)};
    *(ushort4*)(QXbf + off) = yb;
}

// ---------------- lnout: S=(Z+x)*keep; LN -> next-Q/VIN (i=0) or d_out f32 (i=1) ----------------
__global__ __launch_bounds__(256)
void lnout_kernel(const unsigned short* __restrict__ Zbf,
                  unsigned short* QXbf,                       // in: x resid; out (i=0): next Q
                  const unsigned short* __restrict__ Tbf,
                  const float* __restrict__ keepv,
                  const float* __restrict__ lnG, const float* __restrict__ lnB,
                  float* __restrict__ outF,                   // d_out (i=1) or null
                  unsigned short* __restrict__ outVIN) {      // next VIN (i=0) or null
    int tok  = blockIdx.x * 4 + (threadIdx.x >> 6);
    int lane = threadIdx.x & 63;
    size_t off = (size_t)tok * Hdim + lane * 4;
    ushort4 z = *(const ushort4*)(Zbf + off);
    ushort4 x = *(const ushort4*)(QXbf + off);
    float kf = keepv[tok];
    float4 s = {(bf2f(z.x) + bf2f(x.x)) * kf, (bf2f(z.y) + bf2f(x.y)) * kf,
                (bf2f(z.z) + bf2f(x.z)) * kf, (bf2f(z.w) + bf2f(x.w)) * kf};
    float r0 = s.x + s.y + s.z + s.w;
    float r1 = s.x * s.x + s.y * s.y + s.z * s.z + s.w * s.w;
#pragma unroll
    for (int o = 1; o < 64; o <<= 1) {
        r0 += __shfl_xor(r0, o, 64);
        r1 += __shfl_xor(r1, o, 64);
    }
    float mean = r0 * (1.0f / Hdim);
    float var  = fmaxf(r1 * (1.0f / Hdim) - mean * mean, 0.0f);
    float rstd = rsqrtf(var + 1e-8f);
    float4 g4 = *(const float4*)(lnG + lane * 4);
    float4 b4 = *(const float4*)(lnB + lane * 4);
    float4 y = {(s.x - mean) * rstd * g4.x + b4.x, (s.y - mean) * rstd * g4.y + b4.y,
                (s.z - mean) * rstd * g4.z + b4.z, (s.w - mean) * rstd * g4.w + b4.w};
    if (outF) {
        *(float4*)(outF + off) = y;
    } else {
        ushort4 yb = {f2bf(y.x), f2bf(y.y), f2bf(y.z), f2bf(y.w)};
        *(ushort4*)(QXbf + off) = yb;
        ushort4 t = *(const ushort4*)(Tbf + off);
        ushort4 vb = {f2bf(s.x + bf2f(t.x)), f2bf(s.y + bf2f(t.y)),
                      f2bf(s.z + bf2f(t.z)), f2bf(s.w + bf2f(t.w))};
        *(ushort4*)(outVIN + off) = vb;
    }
}

#define GBM 128
#define GBN 128
#define GBK 32

// ---------------- merged q/k/v GEMM 128x128: blockIdx.z selects operand set ----------------
__global__ __launch_bounds__(256)
void gemm_qkv_kernel(const unsigned short* __restrict__ QXbf,
                     const unsigned short* __restrict__ Tbf,
                     const unsigned short* __restrict__ VINbf,
                     const unsigned short* __restrict__ qW,
                     const unsigned short* __restrict__ kW,
                     const unsigned short* __restrict__ vW,
                     const float* __restrict__ qb, const float* __restrict__ kb,
                     const float* __restrict__ vb,
                     unsigned short* __restrict__ Qbf,
                     unsigned short* __restrict__ Kbf,
                     unsigned short* __restrict__ VT) {
    __shared__ __align__(16) char smem[128 * 136 * 2];
    __bf16 (*As)[GBK] = (__bf16 (*)[GBK])smem;
    __bf16 (*Ws)[GBK] = (__bf16 (*)[GBK])(smem + 8192);
    __bf16 (*Ct)[136] = (__bf16 (*)[136])smem;
    int z = blockIdx.z;
    const unsigned short* A = (z == 0) ? QXbf : (z == 1) ? Tbf : VINbf;
    const unsigned short* W = (z == 0) ? qW : (z == 1) ? kW : vW;
    const float* bias       = (z == 0) ? qb : (z == 1) ? kb : vb;

    int tid = threadIdx.x, lane = tid & 63, w = tid >> 6;
    int wr = w >> 1, wc = w & 1;
    int m0 = blockIdx.y * GBM, n0 = blockIdx.x * GBN;
    f32x4 acc[4][4];
#pragma unroll
    for (int i = 0; i < 4; ++i)
#pragma unroll
        for (int j = 0; j < 4; ++j) acc[i][j] = (f32x4)(0.0f);
    int cA = tid, cB = tid + 256;
    int rA = cA >> 2, kA = (cA & 3) * 8;
    int rB = cB >> 2, kB = (cB & 3) * 8;
    int colq = lane & 15, kq = (lane >> 4) * 8;
    for (int kc = 0; kc < Hdim; kc += GBK) {
        __syncthreads();
        gload16(A + (size_t)(m0 + rA) * Hdim + kc + kA, (__bf16*)As + cA * 8);
        gload16(A + (size_t)(m0 + rB) * Hdim + kc + kB, (__bf16*)As + cB * 8);
        gload16(W + (size_t)(n0 + rA) * Hdim + kc + kA, (__bf16*)Ws + cA * 8);
        gload16(W + (size_t)(n0 + rB) * Hdim + kc + kB, (__bf16*)Ws + cB * 8);
        __syncthreads();
        bf16x8 af[4], bfr[4];
#pragma unroll
        for (int i = 0; i < 4; ++i)
            af[i] = *(const bf16x8*)&As[wr * 64 + i * 16 + colq][kq];
#pragma unroll
        for (int j = 0; j < 4; ++j)
            bfr[j] = *(const bf16x8*)&Ws[wc * 64 + j * 16 + colq][kq];
#pragma unroll
        for (int i = 0; i < 4; ++i)
#pragma unroll
            for (int j = 0; j < 4; ++j)
                acc[i][j] = __builtin_amdgcn_mfma_f32_16x16x32_bf16(af[i], bfr[j], acc[i][j], 0, 0, 0);
    }
    int rowq = (lane >> 4) * 4;
    if (z < 2) {
        unsigned short* outBF = (z == 0) ? Qbf : Kbf;
#pragma unroll
        for (int i = 0; i < 4; ++i)
#pragma unroll
            for (int r = 0; r < 4; ++r) {
                int m = m0 + wr * 64 + i * 16 + rowq + r;
#pragma unroll
                for (int j = 0; j < 4; ++j) {
                    int n = n0 + wc * 64 + j * 16 + colq;
                    outBF[(size_t)m * Hdim + n] = f2bf(acc[i][j][r] + bias[n]);
                }
            }
    } else {
        __syncthreads();   // all frag reads done before Ct overwrites As/Ws
#pragma unroll
        for (int i = 0; i < 4; ++i)
#pragma unroll
            for (int r = 0; r < 4; ++r) {
                int ml = wr * 64 + i * 16 + rowq + r;
#pragma unroll
                for (int j = 0; j < 4; ++j) {
                    int nl = wc * 64 + j * 16 + colq;
                    Ct[nl][ml] = (__bf16)(acc[i][j][r] + bias[n0 + nl]);
                }
            }
        __syncthreads();
        int bb = m0 >> 9, l0 = m0 & 511;
#pragma unroll
        for (int it = 0; it < 8; ++it) {
            int c = tid + it * 256;
            int nl = c >> 4;
            int o8 = (c & 15) * 8;
            int n = n0 + nl;
            int hh = n >> 6, dd = n & 63;
            bf16x8 v = *(const bf16x8*)&Ct[nl][o8];
            *(bf16x8*)(VT + ((((size_t)bb * NHEAD + hh) * HD + dd) * Ldim + l0 + o8)) = v;
        }
    }
}

// ---------------- plain bf16 GEMM 128x128: C = A@W^T + bias [relu] -> bf16 ----------------
__global__ __launch_bounds__(256)
void gemm_plain_kernel(const unsigned short* __restrict__ A,
                       const unsigned short* __restrict__ W,
                       const float* __restrict__ bias,
                       unsigned short* __restrict__ outBF, int doRelu) {
    __shared__ __bf16 As[GBM][GBK];
    __shared__ __bf16 Ws[GBN][GBK];
    int tid = threadIdx.x, lane = tid & 63, w = tid >> 6;
    int wr = w >> 1, wc = w & 1;
    int m0 = blockIdx.y * GBM, n0 = blockIdx.x * GBN;
    f32x4 acc[4][4];
#pragma unroll
    for (int i = 0; i < 4; ++i)
#pragma unroll
        for (int j = 0; j < 4; ++j) acc[i][j] = (f32x4)(0.0f);
    int cA = tid, cB = tid + 256;
    int rA = cA >> 2, kA = (cA & 3) * 8;
    int rB = cB >> 2, kB = (cB & 3) * 8;
    int colq = lane & 15, kq = (lane >> 4) * 8;
    for (int kc = 0; kc < Hdim; kc += GBK) {
        __syncthreads();
        gload16(A + (size_t)(m0 + rA) * Hdim + kc + kA, (__bf16*)As + cA * 8);
        gload16(A + (size_t)(m0 + rB) * Hdim + kc + kB, (__bf16*)As + cB * 8);
        gload16(W + (size_t)(n0 + rA) * Hdim + kc + kA, (__bf16*)Ws + cA * 8);
        gload16(W + (size_t)(n0 + rB) * Hdim + kc + kB, (__bf16*)Ws + cB * 8);
        __syncthreads();
        bf16x8 af[4], bfr[4];
#pragma unroll
        for (int i = 0; i < 4; ++i)
            af[i] = *(const bf16x8*)&As[wr * 64 + i * 16 + colq][kq];
#pragma unroll
        for (int j = 0; j < 4; ++j)
            bfr[j] = *(const bf16x8*)&Ws[wc * 64 + j * 16 + colq][kq];
#pragma unroll
        for (int i = 0; i < 4; ++i)
#pragma unroll
            for (int j = 0; j < 4; ++j)
                acc[i][j] = __builtin_amdgcn_mfma_f32_16x16x32_bf16(af[i], bfr[j], acc[i][j], 0, 0, 0);
    }
    int rowq = (lane >> 4) * 4;
#pragma unroll
    for (int i = 0; i < 4; ++i)
#pragma unroll
        for (int r = 0; r < 4; ++r) {
            int m = m0 + wr * 64 + i * 16 + rowq + r;
#pragma unroll
            for (int j = 0; j < 4; ++j) {
                int n = n0 + wc * 64 + j * 16 + colq;
                float v = acc[i][j][r] + bias[n];
                if (doRelu) v = fmaxf(v, 0.0f);
                outBF[(size_t)m * Hdim + n] = f2bf(v);
            }
        }
}

// ---------------- persistent per-(b,h) gated causal flash attention ----------------
#define AK_STRIDE 72
#define AV_STRIDE 520
#define ATTN_LDS (512 * AK_STRIDE * 2 + 64 * AV_STRIDE * 2 + 128 * AK_STRIDE * 2)
__global__ __launch_bounds__(512, 1)
void attn_mfma_kernel(const unsigned short* __restrict__ Qg,
                      const unsigned short* __restrict__ Kg,
                      const unsigned short* __restrict__ VTg,
                      const float* __restrict__ gates,
                      unsigned short* __restrict__ Ob, int blk) {
    extern __shared__ __align__(16) char smem[];
    __bf16 (*Ks)[AK_STRIDE]  = (__bf16 (*)[AK_STRIDE])smem;
    __bf16 (*VTs)[AV_STRIDE] = (__bf16 (*)[AV_STRIDE])(smem + 512 * AK_STRIDE * 2);
    __bf16 (*QPs)[AK_STRIDE] = (__bf16 (*)[AK_STRIDE])(smem + 512 * AK_STRIDE * 2 + 64 * AV_STRIDE * 2);
    int h = blockIdx.x & 3, b = blockIdx.x >> 2;
    int tid = threadIdx.x, lane = tid & 63, w = tid >> 6;
    int colq = lane & 15, grp = lane >> 4;
    int rowq = grp * 4, kq = grp * 8;

    size_t baseK = (size_t)b * Ldim * Hdim + h * HD;
#pragma unroll
    for (int it = 0; it < 8; ++it) {
        int c = tid + it * 512;
        int r = c >> 3, o = (c & 7) * 8;
        *(bf16x8*)&Ks[r][o] = *(const bf16x8*)(Kg + baseK + (size_t)r * Hdim + o);
    }
    size_t baseV = ((size_t)b * NHEAD + h) * HD * Ldim;
#pragma unroll
    for (int it = 0; it < 8; ++it) {
        int c = tid + it * 512;
        int d = c >> 6, k = (c & 63) * 8;
        *(bf16x8*)&VTs[d][k] = *(const bf16x8*)(VTg + baseV + (size_t)d * Ldim + k);
    }

    const float lscale = 0.125f * 1.44269504f;
    for (int qt = 0; qt < 4; ++qt) {
        int q0 = qt * 128;
        __syncthreads();
#pragma unroll
        for (int it = 0; it < 2; ++it) {
            int c = tid + it * 512;
            int r = c >> 3, o = (c & 7) * 8;
            *(bf16x8*)&QPs[r][o] =
                *(const bf16x8*)(Qg + (size_t)(b * Ldim + q0 + r) * Hdim + h * HD + o);
        }
        float gql[4];
#pragma unroll
        for (int r = 0; r < 4; ++r)
            gql[r] = gates[((size_t)b * Ldim + q0 + w * 16 + rowq + r) * 2 + blk] * lscale;
        __syncthreads();
        bf16x8 afq0 = *(const bf16x8*)&QPs[w * 16 + colq][kq];
        bf16x8 afq1 = *(const bf16x8*)&QPs[w * 16 + colq][32 + kq];

        float lrun[4] = {0.0f, 0.0f, 0.0f, 0.0f};
        f32x4 accO[4];
#pragma unroll
        for (int jd = 0; jd < 4; ++jd) accO[jd] = (f32x4)(0.0f);

        int nkt = 2 * qt + 2;
        for (int kt = 0; kt < nkt; ++kt) {
            int k0 = kt * 64;
            f32x4 s[4];
#pragma unroll
            for (int j = 0; j < 4; ++j) s[j] = (f32x4)(0.0f);
#pragma unroll
            for (int j = 0; j < 4; ++j) {
                bf16x8 bk0 = *(const bf16x8*)&Ks[k0 + j * 16 + colq][kq];
                bf16x8 bk1 = *(const bf16x8*)&Ks[k0 + j * 16 + colq][32 + kq];
                s[j] = __builtin_amdgcn_mfma_f32_16x16x32_bf16(afq0, bk0, s[j], 0, 0, 0);
                s[j] = __builtin_amdgcn_mfma_f32_16x16x32_bf16(afq1, bk1, s[j], 0, 0, 0);
            }
            float gkv[4];
#pragma unroll
            for (int j = 0; j < 4; ++j)
                gkv[j] = gates[((size_t)b * Ldim + k0 + j * 16 + colq) * 2 + blk];
#pragma unroll
            for (int r = 0; r < 4; ++r) {
                int qg = q0 + w * 16 + rowq + r;
                float su = 0.0f;
                float p[4];
#pragma unroll
                for (int j = 0; j < 4; ++j) {
                    int kg = k0 + j * 16 + colq;
                    float v = s[j][r] * gql[r] * gkv[j];
                    v = (kg > qg) ? -1e38f : v;
                    float e = exp2f(v);
                    p[j] = e;
                    su += e;
                }
#pragma unroll
                for (int off = 1; off < 16; off <<= 1)
                    su += __shfl_xor(su, off, 16);
                lrun[r] += su;
#pragma unroll
                for (int j = 0; j < 4; ++j)
                    QPs[w * 16 + rowq + r][j * 16 + colq] = (__bf16)p[j];
            }
            bf16x8 ap0 = *(const bf16x8*)&QPs[w * 16 + colq][kq];
            bf16x8 ap1 = *(const bf16x8*)&QPs[w * 16 + colq][32 + kq];
#pragma unroll
            for (int jd = 0; jd < 4; ++jd) {
                bf16x8 bv0 = *(const bf16x8*)&VTs[jd * 16 + colq][k0 + kq];
                bf16x8 bv1 = *(const bf16x8*)&VTs[jd * 16 + colq][k0 + 32 + kq];
                accO[jd] = __builtin_amdgcn_mfma_f32_16x16x32_bf16(ap0, bv0, accO[jd], 0, 0, 0);
                accO[jd] = __builtin_amdgcn_mfma_f32_16x16x32_bf16(ap1, bv1, accO[jd], 0, 0, 0);
            }
        }
#pragma unroll
        for (int r = 0; r < 4; ++r) {
            float inv = 1.0f / lrun[r];
#pragma unroll
            for (int jd = 0; jd < 4; ++jd)
                Ob[(size_t)(b * Ldim + q0 + w * 16 + rowq + r) * Hdim + h * HD + jd * 16 + colq] =
                    f2bf(accO[jd][r] * inv);
        }
    }
}

// ---------------- launcher ----------------
extern "C" void kernel_launch(void* const* d_in, const int* in_sizes, int n_in,
                              void* d_out, int out_size, void* d_ws, size_t ws_size,
                              hipStream_t stream) {
    const int*   seqs_data = (const int*)d_in[0];
    const float* seqs      = (const float*)d_in[1];
    const int*   position  = (const int*)d_in[2];
    const float* time_emb  = (const float*)d_in[3];
    const float* pos_table = (const float*)d_in[4];
    const float* gate_W    = (const float*)d_in[5];
    const float* gate_b    = (const float*)d_in[6];
    const float* ln_attn_g = (const float*)d_in[7];
    const float* ln_attn_b = (const float*)d_in[8];
    const float* qW        = (const float*)d_in[9];
    const float* qb        = (const float*)d_in[10];
    const float* kW        = (const float*)d_in[11];
    const float* kb        = (const float*)d_in[12];
    const float* vW        = (const float*)d_in[13];
    const float* vb        = (const float*)d_in[14];
    const float* ln_ffn_g  = (const float*)d_in[15];
    const float* ln_ffn_b  = (const float*)d_in[16];
    const float* c1W       = (const float*)d_in[17];
    const float* c1b       = (const float*)d_in[18];
    const float* c2W       = (const float*)d_in[19];
    const float* c2b       = (const float*)d_in[20];
    const float* last_g    = (const float*)d_in[21];
    const float* last_b    = (const float*)d_in[22];

    size_t BUF = (size_t)NTOK * Hdim;
    float* fws = (float*)d_ws;
    float* GATES = fws;                       // NTOK*2
    float* KEEP  = GATES + (size_t)NTOK * 2;  // NTOK
    unsigned short* bws   = (unsigned short*)(KEEP + NTOK);
    unsigned short* Tbf   = bws;
    unsigned short* QXbf  = Tbf + BUF;        // Q / x / next-Q (in place)
    unsigned short* VINbf = QXbf + BUF;
    unsigned short* HIDbf = VINbf + BUF;
    unsigned short* Qbf   = HIDbf + BUF;
    unsigned short* Kbf   = Qbf + BUF;
    unsigned short* VTbf  = Kbf + BUF;        // V^T [B][NH][HD][L]
    unsigned short* QAbf  = VTbf + BUF;
    unsigned short* Zbf   = QAbf + BUF;       // c2 GEMM output
    unsigned short* Wbf   = Zbf + BUF;
    size_t WB = (size_t)Hdim * Hdim;
    unsigned short* qWbf  = Wbf;
    unsigned short* kWbf  = Wbf + 2 * WB;
    unsigned short* vWbf  = Wbf + 4 * WB;
    unsigned short* c1Wbf = Wbf + 6 * WB;
    unsigned short* c2Wbf = Wbf + 8 * WB;

    castw_kernel<<<dim3(128, 5), 256, 0, stream>>>(qW, kW, vW, c1W, c2W, Wbf);
    prep_ln_kernel<<<NTOK / 4, 256, 0, stream>>>(seqs_data, seqs, position, time_emb,
                                                 pos_table, gate_W, gate_b,
                                                 ln_attn_g, ln_attn_b,
                                                 Tbf, QXbf, VINbf, GATES, KEEP);

    dim3 qkvgrid(Hdim / GBN, NTOK / GBM, 3);   // (2, 256, 3)
    dim3 ggrid(Hdim / GBN, NTOK / GBM);        // (2, 256)
    for (int i = 0; i < 2; ++i) {
        gemm_qkv_kernel<<<qkvgrid, 256, 0, stream>>>(QXbf, Tbf, VINbf,
                                                     qWbf + i * WB, kWbf + i * WB, vWbf + i * WB,
                                                     qb + i * Hdim, kb + i * Hdim, vb + i * Hdim,
                                                     Qbf, Kbf, VTbf);
        attn_mfma_kernel<<<Bdim * NHEAD, 512, ATTN_LDS, stream>>>(Qbf, Kbf, VTbf, GATES, QAbf, i);
        ln2_kernel<<<NTOK / 4, 256, 0, stream>>>(QXbf, QAbf,
                                                 ln_ffn_g + i * Hdim, ln_ffn_b + i * Hdim);
        gemm_plain_kernel<<<ggrid, 256, 0, stream>>>(QXbf, c1Wbf + i * WB, c1b + i * Hdim, HIDbf, 1);
        gemm_plain_kernel<<<ggrid, 256, 0, stream>>>(HIDbf, c2Wbf + i * WB, c2b + i * Hdim, Zbf, 0);
        if (i == 0) {
            lnout_kernel<<<NTOK / 4, 256, 0, stream>>>(
                Zbf, QXbf, Tbf, KEEP,
                ln_attn_g + Hdim, ln_attn_b + Hdim,
                nullptr, VINbf);
        } else {
            lnout_kernel<<<NTOK / 4, 256, 0, stream>>>(
                Zbf, QXbf, Tbf, KEEP,
                last_g, last_b,
                (float*)d_out, nullptr);
        }
    }
}

// Round 10
// 383.874 us; speedup vs baseline: 1.1824x; 1.0168x over previous
//
#include <hip/hip_runtime.h>
#include <hip/hip_bf16.h>
#include <math.h>

// Problem constants
#define NTOK 32768      // B*L = 64*512
#define Hdim 256
#define Ldim 512
#define Bdim 64
#define NHEAD 4
#define HD 64
#define PADV 49999      // ITEMNUM-1

typedef __bf16 bf16x8 __attribute__((ext_vector_type(8)));
typedef float  f32x4  __attribute__((ext_vector_type(4)));

__device__ __forceinline__ unsigned short f2bf(float f) {
    unsigned int u = __float_as_uint(f);
    unsigned int r = (u + 0x7fffu + ((u >> 16) & 1u)) >> 16;
    return (unsigned short)r;
}
__device__ __forceinline__ float bf2f(unsigned short u) {
    return __uint_as_float(((unsigned int)u) << 16);
}

// async global->LDS, 16B per lane (dest must be wave-uniform base + lane*16)
__device__ __forceinline__ void gload16(const void* g, void* l) {
    __builtin_amdgcn_global_load_lds((const __attribute__((address_space(1))) unsigned int*)g,
                                     (__attribute__((address_space(3))) unsigned int*)l,
                                     16, 0, 0);
}

// ---------------- weight cast: 5 matrices x (2*256*256) f32 -> bf16 ----------------
__global__ __launch_bounds__(256)
void castw_kernel(const float* __restrict__ q, const float* __restrict__ k,
                  const float* __restrict__ v, const float* __restrict__ c1,
                  const float* __restrict__ c2, unsigned short* __restrict__ dst) {
    const float* srcs[5] = {q, k, v, c1, c2};
    const float* s = srcs[blockIdx.y];
    int idx = blockIdx.x * 1024 + threadIdx.x * 4;
    float4 f = *(const float4*)(s + idx);
    unsigned short* d = dst + (size_t)blockIdx.y * 131072 + idx;
    d[0] = f2bf(f.x); d[1] = f2bf(f.y); d[2] = f2bf(f.z); d[3] = f2bf(f.w);
}

// ---------------- prep + ln_attn[0] fused (wave per token), all-bf16 outputs ----------------
__global__ __launch_bounds__(256)
void prep_ln_kernel(const int* __restrict__ seqs_data, const float* __restrict__ seqs,
                    const int* __restrict__ position, const float* __restrict__ time_emb,
                    const float* __restrict__ pos_table, const float* __restrict__ gate_W,
                    const float* __restrict__ gate_b,
                    const float* __restrict__ lnG, const float* __restrict__ lnB,
                    unsigned short* __restrict__ Tbf,
                    unsigned short* __restrict__ QXbf,
                    unsigned short* __restrict__ VINbf,
                    float* __restrict__ gates, float* __restrict__ keepv) {
    int tok  = blockIdx.x * 4 + (threadIdx.x >> 6);
    int lane = threadIdx.x & 63;
    size_t off = (size_t)tok * Hdim + lane * 4;
    int pos = position[tok];
    float4 pe = *(const float4*)(pos_table + (size_t)pos * Hdim + lane * 4);
    float4 sq = *(const float4*)(seqs + off);
    float4 tm = *(const float4*)(time_emb + off);
    float keep = (seqs_data[tok] != PADV) ? 1.0f : 0.0f;
    float4 t = {tm.x + pe.x, tm.y + pe.y, tm.z + pe.z, tm.w + pe.w};
    float4 s = {(sq.x + pe.x) * keep, (sq.y + pe.y) * keep,
                (sq.z + pe.z) * keep, (sq.w + pe.w) * keep};
    ushort4 tb = {f2bf(t.x), f2bf(t.y), f2bf(t.z), f2bf(t.w)};
    *(ushort4*)(Tbf + off) = tb;
    float4 gw0 = *(const float4*)(gate_W + lane * 4);
    float4 gw1 = *(const float4*)(gate_W + Hdim + lane * 4);
    float r0 = s.x + s.y + s.z + s.w;
    float r1 = s.x * s.x + s.y * s.y + s.z * s.z + s.w * s.w;
    float r2 = t.x * gw0.x + t.y * gw0.y + t.z * gw0.z + t.w * gw0.w;
    float r3 = t.x * gw1.x + t.y * gw1.y + t.z * gw1.z + t.w * gw1.w;
#pragma unroll
    for (int o = 1; o < 64; o <<= 1) {
        r0 += __shfl_xor(r0, o, 64);
        r1 += __shfl_xor(r1, o, 64);
        r2 += __shfl_xor(r2, o, 64);
        r3 += __shfl_xor(r3, o, 64);
    }
    float mean = r0 * (1.0f / Hdim);
    float var  = fmaxf(r1 * (1.0f / Hdim) - mean * mean, 0.0f);
    float rstd = rsqrtf(var + 1e-8f);
    if (lane == 0) {
        gates[(size_t)tok * 2 + 0] = 1.0f / (1.0f + __expf(-(r2 + gate_b[0])));
        gates[(size_t)tok * 2 + 1] = 1.0f / (1.0f + __expf(-(r3 + gate_b[1])));
        keepv[tok] = keep;
    }
    float4 g4 = *(const float4*)(lnG + lane * 4);
    float4 b4 = *(const float4*)(lnB + lane * 4);
    float4 y = {(s.x - mean) * rstd * g4.x + b4.x, (s.y - mean) * rstd * g4.y + b4.y,
                (s.z - mean) * rstd * g4.z + b4.z, (s.w - mean) * rstd * g4.w + b4.w};
    ushort4 yb = {f2bf(y.x), f2bf(y.y), f2bf(y.z), f2bf(y.w)};
    *(ushort4*)(QXbf + off) = yb;
    ushort4 vb = {f2bf(s.x + t.x), f2bf(s.y + t.y), f2bf(s.z + t.z), f2bf(s.w + t.w)};
    *(ushort4*)(VINbf + off) = vb;
}

// ---------------- ln_ffn: x = Q(bf16) + QA(bf16); LN -> QXbf in place ----------------
__global__ __launch_bounds__(256)
void ln2_kernel(unsigned short* QXbf, const unsigned short* __restrict__ QA,
                const float* __restrict__ lnG, const float* __restrict__ lnB) {
    int tok  = blockIdx.x * 4 + (threadIdx.x >> 6);
    int lane = threadIdx.x & 63;
    size_t off = (size_t)tok * Hdim + lane * 4;
    ushort4 q = *(const ushort4*)(QXbf + off);
    ushort4 a = *(const ushort4*)(QA + off);
    float4 x = {bf2f(q.x) + bf2f(a.x), bf2f(q.y) + bf2f(a.y),
                bf2f(q.z) + bf2f(a.z), bf2f(q.w) + bf2f(a.w)};
    float r0 = x.x + x.y + x.z + x.w;
    float r1 = x.x * x.x + x.y * x.y + x.z * x.z + x.w * x.w;
#pragma unroll
    for (int o = 1; o < 64; o <<= 1) {
        r0 += __shfl_xor(r0, o, 64);
        r1 += __shfl_xor(r1, o, 64);
    }
    float mean = r0 * (1.0f / Hdim);
    float var  = fmaxf(r1 * (1.0f / Hdim) - mean * mean, 0.0f);
    float rstd = rsqrtf(var + 1e-8f);
    float4 g4 = *(const float4*)(lnG + lane * 4);
    float4 b4 = *(const float4*)(lnB + lane * 4);
    ushort4 yb = {f2bf((x.x - mean) * rstd * g4.x + b4.x),
                  f2bf((x.y - mean) * rstd * g4.y + b4.y),
                  f2bf((x.z - mean) * rstd * g4.z + b4.z),
                  f2bf((x.w - mean) * rstd * g4.w + b4.w)};
    *(ushort4*)(QXbf + off) = yb;
}

// ---------------- lnout: S=(Z+x)*keep; LN -> next-Q/VIN (i=0) or d_out f32 (i=1) ----------------
__global__ __launch_bounds__(256)
void lnout_kernel(const unsigned short* __restrict__ Zbf,
                  unsigned short* QXbf,
                  const unsigned short* __restrict__ Tbf,
                  const float* __restrict__ keepv,
                  const float* __restrict__ lnG, const float* __restrict__ lnB,
                  float* __restrict__ outF,
                  unsigned short* __restrict__ outVIN) {
    int tok  = blockIdx.x * 4 + (threadIdx.x >> 6);
    int lane = threadIdx.x & 63;
    size_t off = (size_t)tok * Hdim + lane * 4;
    ushort4 z = *(const ushort4*)(Zbf + off);
    ushort4 x = *(const ushort4*)(QXbf + off);
    float kf = keepv[tok];
    float4 s = {(bf2f(z.x) + bf2f(x.x)) * kf, (bf2f(z.y) + bf2f(x.y)) * kf,
                (bf2f(z.z) + bf2f(x.z)) * kf, (bf2f(z.w) + bf2f(x.w)) * kf};
    float r0 = s.x + s.y + s.z + s.w;
    float r1 = s.x * s.x + s.y * s.y + s.z * s.z + s.w * s.w;
#pragma unroll
    for (int o = 1; o < 64; o <<= 1) {
        r0 += __shfl_xor(r0, o, 64);
        r1 += __shfl_xor(r1, o, 64);
    }
    float mean = r0 * (1.0f / Hdim);
    float var  = fmaxf(r1 * (1.0f / Hdim) - mean * mean, 0.0f);
    float rstd = rsqrtf(var + 1e-8f);
    float4 g4 = *(const float4*)(lnG + lane * 4);
    float4 b4 = *(const float4*)(lnB + lane * 4);
    float4 y = {(s.x - mean) * rstd * g4.x + b4.x, (s.y - mean) * rstd * g4.y + b4.y,
                (s.z - mean) * rstd * g4.z + b4.z, (s.w - mean) * rstd * g4.w + b4.w};
    if (outF) {
        *(float4*)(outF + off) = y;
    } else {
        ushort4 yb = {f2bf(y.x), f2bf(y.y), f2bf(y.z), f2bf(y.w)};
        *(ushort4*)(QXbf + off) = yb;
        ushort4 t = *(const ushort4*)(Tbf + off);
        ushort4 vb = {f2bf(s.x + bf2f(t.x)), f2bf(s.y + bf2f(t.y)),
                      f2bf(s.z + bf2f(t.z)), f2bf(s.w + bf2f(t.w))};
        *(ushort4*)(outVIN + off) = vb;
    }
}

#define GBM 128
#define GBN 128
#define GBK 32

// ---------------- merged q/k/v GEMM 128x128: blockIdx.z selects operand set ----------------
__global__ __launch_bounds__(256)
void gemm_qkv_kernel(const unsigned short* __restrict__ QXbf,
                     const unsigned short* __restrict__ Tbf,
                     const unsigned short* __restrict__ VINbf,
                     const unsigned short* __restrict__ qW,
                     const unsigned short* __restrict__ kW,
                     const unsigned short* __restrict__ vW,
                     const float* __restrict__ qb, const float* __restrict__ kb,
                     const float* __restrict__ vb,
                     unsigned short* __restrict__ Qbf,
                     unsigned short* __restrict__ Kbf,
                     unsigned short* __restrict__ VT) {
    __shared__ __align__(16) char smem[128 * 136 * 2];
    __bf16 (*As)[GBK] = (__bf16 (*)[GBK])smem;
    __bf16 (*Ws)[GBK] = (__bf16 (*)[GBK])(smem + 8192);
    __bf16 (*Ct)[136] = (__bf16 (*)[136])smem;
    int z = blockIdx.z;
    const unsigned short* A = (z == 0) ? QXbf : (z == 1) ? Tbf : VINbf;
    const unsigned short* W = (z == 0) ? qW : (z == 1) ? kW : vW;
    const float* bias       = (z == 0) ? qb : (z == 1) ? kb : vb;

    int tid = threadIdx.x, lane = tid & 63, w = tid >> 6;
    int wr = w >> 1, wc = w & 1;
    int m0 = blockIdx.y * GBM, n0 = blockIdx.x * GBN;
    f32x4 acc[4][4];
#pragma unroll
    for (int i = 0; i < 4; ++i)
#pragma unroll
        for (int j = 0; j < 4; ++j) acc[i][j] = (f32x4)(0.0f);
    int cA = tid, cB = tid + 256;
    int rA = cA >> 2, kA = (cA & 3) * 8;
    int rB = cB >> 2, kB = (cB & 3) * 8;
    int colq = lane & 15, kq = (lane >> 4) * 8;
    for (int kc = 0; kc < Hdim; kc += GBK) {
        __syncthreads();
        gload16(A + (size_t)(m0 + rA) * Hdim + kc + kA, (__bf16*)As + cA * 8);
        gload16(A + (size_t)(m0 + rB) * Hdim + kc + kB, (__bf16*)As + cB * 8);
        gload16(W + (size_t)(n0 + rA) * Hdim + kc + kA, (__bf16*)Ws + cA * 8);
        gload16(W + (size_t)(n0 + rB) * Hdim + kc + kB, (__bf16*)Ws + cB * 8);
        __syncthreads();
        bf16x8 af[4], bfr[4];
#pragma unroll
        for (int i = 0; i < 4; ++i)
            af[i] = *(const bf16x8*)&As[wr * 64 + i * 16 + colq][kq];
#pragma unroll
        for (int j = 0; j < 4; ++j)
            bfr[j] = *(const bf16x8*)&Ws[wc * 64 + j * 16 + colq][kq];
#pragma unroll
        for (int i = 0; i < 4; ++i)
#pragma unroll
            for (int j = 0; j < 4; ++j)
                acc[i][j] = __builtin_amdgcn_mfma_f32_16x16x32_bf16(af[i], bfr[j], acc[i][j], 0, 0, 0);
    }
    int rowq = (lane >> 4) * 4;
    if (z < 2) {
        unsigned short* outBF = (z == 0) ? Qbf : Kbf;
#pragma unroll
        for (int i = 0; i < 4; ++i)
#pragma unroll
            for (int r = 0; r < 4; ++r) {
                int m = m0 + wr * 64 + i * 16 + rowq + r;
#pragma unroll
                for (int j = 0; j < 4; ++j) {
                    int n = n0 + wc * 64 + j * 16 + colq;
                    outBF[(size_t)m * Hdim + n] = f2bf(acc[i][j][r] + bias[n]);
                }
            }
    } else {
        __syncthreads();
#pragma unroll
        for (int i = 0; i < 4; ++i)
#pragma unroll
            for (int r = 0; r < 4; ++r) {
                int ml = wr * 64 + i * 16 + rowq + r;
#pragma unroll
                for (int j = 0; j < 4; ++j) {
                    int nl = wc * 64 + j * 16 + colq;
                    Ct[nl][ml] = (__bf16)(acc[i][j][r] + bias[n0 + nl]);
                }
            }
        __syncthreads();
        int bb = m0 >> 9, l0 = m0 & 511;
#pragma unroll
        for (int it = 0; it < 8; ++it) {
            int c = tid + it * 256;
            int nl = c >> 4;
            int o8 = (c & 15) * 8;
            int n = n0 + nl;
            int hh = n >> 6, dd = n & 63;
            bf16x8 v = *(const bf16x8*)&Ct[nl][o8];
            *(bf16x8*)(VT + ((((size_t)bb * NHEAD + hh) * HD + dd) * Ldim + l0 + o8)) = v;
        }
    }
}

// ---------------- plain bf16 GEMM 128x128: C = A@W^T + bias [relu] -> bf16 ----------------
__global__ __launch_bounds__(256)
void gemm_plain_kernel(const unsigned short* __restrict__ A,
                       const unsigned short* __restrict__ W,
                       const float* __restrict__ bias,
                       unsigned short* __restrict__ outBF, int doRelu) {
    __shared__ __bf16 As[GBM][GBK];
    __shared__ __bf16 Ws[GBN][GBK];
    int tid = threadIdx.x, lane = tid & 63, w = tid >> 6;
    int wr = w >> 1, wc = w & 1;
    int m0 = blockIdx.y * GBM, n0 = blockIdx.x * GBN;
    f32x4 acc[4][4];
#pragma unroll
    for (int i = 0; i < 4; ++i)
#pragma unroll
        for (int j = 0; j < 4; ++j) acc[i][j] = (f32x4)(0.0f);
    int cA = tid, cB = tid + 256;
    int rA = cA >> 2, kA = (cA & 3) * 8;
    int rB = cB >> 2, kB = (cB & 3) * 8;
    int colq = lane & 15, kq = (lane >> 4) * 8;
    for (int kc = 0; kc < Hdim; kc += GBK) {
        __syncthreads();
        gload16(A + (size_t)(m0 + rA) * Hdim + kc + kA, (__bf16*)As + cA * 8);
        gload16(A + (size_t)(m0 + rB) * Hdim + kc + kB, (__bf16*)As + cB * 8);
        gload16(W + (size_t)(n0 + rA) * Hdim + kc + kA, (__bf16*)Ws + cA * 8);
        gload16(W + (size_t)(n0 + rB) * Hdim + kc + kB, (__bf16*)Ws + cB * 8);
        __syncthreads();
        bf16x8 af[4], bfr[4];
#pragma unroll
        for (int i = 0; i < 4; ++i)
            af[i] = *(const bf16x8*)&As[wr * 64 + i * 16 + colq][kq];
#pragma unroll
        for (int j = 0; j < 4; ++j)
            bfr[j] = *(const bf16x8*)&Ws[wc * 64 + j * 16 + colq][kq];
#pragma unroll
        for (int i = 0; i < 4; ++i)
#pragma unroll
            for (int j = 0; j < 4; ++j)
                acc[i][j] = __builtin_amdgcn_mfma_f32_16x16x32_bf16(af[i], bfr[j], acc[i][j], 0, 0, 0);
    }
    int rowq = (lane >> 4) * 4;
#pragma unroll
    for (int i = 0; i < 4; ++i)
#pragma unroll
        for (int r = 0; r < 4; ++r) {
            int m = m0 + wr * 64 + i * 16 + rowq + r;
#pragma unroll
            for (int j = 0; j < 4; ++j) {
                int n = n0 + wc * 64 + j * 16 + colq;
                float v = acc[i][j][r] + bias[n];
                if (doRelu) v = fmaxf(v, 0.0f);
                outBF[(size_t)m * Hdim + n] = f2bf(v);
            }
        }
}

// ---------------- persistent per-(b,h) attention, barrier-free wave-autonomous ----------------
// 256 blocks x 512 threads. LDS: K[512][72]=73728 + VT[64][520]=66560 + P[128][72]=18432
// After one staging barrier, each wave runs fully independently:
//  - Q fragments in registers
//  - wave-private 16-row P strip (within-wave LDS FIFO ordering, no barriers)
//  - wave w handles 2 strips (32 rows) of qt-tiles {0,3} (w<4) or {1,2} (w>=4)
//  - skips above-diagonal kt-tiles; mask only on the diagonal tile
#define AK_STRIDE 72
#define AV_STRIDE 520
#define ATTN_LDS (512 * AK_STRIDE * 2 + 64 * AV_STRIDE * 2 + 128 * AK_STRIDE * 2)
__global__ __launch_bounds__(512, 1)
void attn_mfma_kernel(const unsigned short* __restrict__ Qg,
                      const unsigned short* __restrict__ Kg,
                      const unsigned short* __restrict__ VTg,
                      const float* __restrict__ gates,
                      unsigned short* __restrict__ Ob, int blk) {
    extern __shared__ __align__(16) char smem[];
    __bf16 (*Ks)[AK_STRIDE]  = (__bf16 (*)[AK_STRIDE])smem;
    __bf16 (*VTs)[AV_STRIDE] = (__bf16 (*)[AV_STRIDE])(smem + 512 * AK_STRIDE * 2);
    __bf16 (*Ps)[AK_STRIDE]  = (__bf16 (*)[AK_STRIDE])(smem + 512 * AK_STRIDE * 2 + 64 * AV_STRIDE * 2);
    int h = blockIdx.x & 3, b = blockIdx.x >> 2;
    int tid = threadIdx.x, lane = tid & 63, w = tid >> 6;
    int colq = lane & 15, grp = lane >> 4;
    int rowq = grp * 4, kq = grp * 8;

    // stage K (512x64) and V^T (64x512) once
    size_t baseK = (size_t)b * Ldim * Hdim + h * HD;
#pragma unroll
    for (int it = 0; it < 8; ++it) {
        int c = tid + it * 512;
        int r = c >> 3, o = (c & 7) * 8;
        *(bf16x8*)&Ks[r][o] = *(const bf16x8*)(Kg + baseK + (size_t)r * Hdim + o);
    }
    size_t baseV = ((size_t)b * NHEAD + h) * HD * Ldim;
#pragma unroll
    for (int it = 0; it < 8; ++it) {
        int c = tid + it * 512;
        int d = c >> 6, k = (c & 63) * 8;
        *(bf16x8*)&VTs[d][k] = *(const bf16x8*)(VTg + baseV + (size_t)d * Ldim + k);
    }
    __syncthreads();   // the ONLY barrier

    const float lscale = 0.125f * 1.44269504f;
    int wq = w & 3;               // 32-row block within the 128-row qt-tile
    int diagBand = wq >> 1;       // both strips of a wave share one 64-row diag band

    for (int p = 0; p < 2; ++p) {
        // balanced qt assignment: waves 0-3 -> {0,3}, waves 4-7 -> {1,2}
        int qt = (w < 4) ? (p ? 3 : 0) : (p ? 2 : 1);
        int q0 = qt * 128 + wq * 32;     // wave's 32 rows: q0 .. q0+31 (2 strips)

        // Q fragments from global (registers only)
        bf16x8 afq[2][2];
        float gql[2][4];
#pragma unroll
        for (int s = 0; s < 2; ++s) {
            size_t qrow = (size_t)(b * Ldim + q0 + s * 16 + colq) * Hdim + h * HD;
            afq[s][0] = *(const bf16x8*)(Qg + qrow + kq);
            afq[s][1] = *(const bf16x8*)(Qg + qrow + 32 + kq);
#pragma unroll
            for (int r = 0; r < 4; ++r)
                gql[s][r] = gates[((size_t)b * Ldim + q0 + s * 16 + rowq + r) * 2 + blk] * lscale;
        }

        float lrun[2][4];
        f32x4 accO[2][4];
#pragma unroll
        for (int s = 0; s < 2; ++s)
#pragma unroll
            for (int r = 0; r < 4; ++r) lrun[s][r] = 0.0f;
#pragma unroll
        for (int s = 0; s < 2; ++s)
#pragma unroll
            for (int jd = 0; jd < 4; ++jd) accO[s][jd] = (f32x4)(0.0f);

        int nfull = qt * 2 + diagBand;   // full (unmasked) 64-wide kt tiles
        for (int kt = 0; kt <= nfull; ++kt) {
            int k0 = kt * 64;
            bool diag = (kt == nfull);
            // S = Q K^T for both strips (32 independent MFMAs)
            f32x4 sv[2][4];
#pragma unroll
            for (int s = 0; s < 2; ++s)
#pragma unroll
                for (int j = 0; j < 4; ++j) sv[s][j] = (f32x4)(0.0f);
#pragma unroll
            for (int j = 0; j < 4; ++j) {
                bf16x8 bk0 = *(const bf16x8*)&Ks[k0 + j * 16 + colq][kq];
                bf16x8 bk1 = *(const bf16x8*)&Ks[k0 + j * 16 + colq][32 + kq];
#pragma unroll
                for (int s = 0; s < 2; ++s) {
                    sv[s][j] = __builtin_amdgcn_mfma_f32_16x16x32_bf16(afq[s][0], bk0, sv[s][j], 0, 0, 0);
                    sv[s][j] = __builtin_amdgcn_mfma_f32_16x16x32_bf16(afq[s][1], bk1, sv[s][j], 0, 0, 0);
                }
            }
            float gkv[4];
#pragma unroll
            for (int j = 0; j < 4; ++j)
                gkv[j] = gates[((size_t)b * Ldim + k0 + j * 16 + colq) * 2 + blk];

            // per strip: softmax -> P strip -> PV (wave-private, barrier-free)
#pragma unroll
            for (int s = 0; s < 2; ++s) {
#pragma unroll
                for (int r = 0; r < 4; ++r) {
                    float su = 0.0f;
                    float p4[4];
                    if (diag) {
                        int qg = q0 + s * 16 + rowq + r;
#pragma unroll
                        for (int j = 0; j < 4; ++j) {
                            float v = sv[s][j][r] * gql[s][r] * gkv[j];
                            v = (k0 + j * 16 + colq > qg) ? -1e38f : v;
                            float e = exp2f(v);
                            p4[j] = e;
                            su += e;
                        }
                    } else {
#pragma unroll
                        for (int j = 0; j < 4; ++j) {
                            float e = exp2f(sv[s][j][r] * gql[s][r] * gkv[j]);
                            p4[j] = e;
                            su += e;
                        }
                    }
#pragma unroll
                    for (int off = 1; off < 16; off <<= 1)
                        su += __shfl_xor(su, off, 16);
                    lrun[s][r] += su;
#pragma unroll
                    for (int j = 0; j < 4; ++j)
                        Ps[w * 16 + rowq + r][j * 16 + colq] = (__bf16)p4[j];
                }
                bf16x8 ap0 = *(const bf16x8*)&Ps[w * 16 + colq][kq];
                bf16x8 ap1 = *(const bf16x8*)&Ps[w * 16 + colq][32 + kq];
#pragma unroll
                for (int jd = 0; jd < 4; ++jd) {
                    bf16x8 bv0 = *(const bf16x8*)&VTs[jd * 16 + colq][k0 + kq];
                    bf16x8 bv1 = *(const bf16x8*)&VTs[jd * 16 + colq][k0 + 32 + kq];
                    accO[s][jd] = __builtin_amdgcn_mfma_f32_16x16x32_bf16(ap0, bv0, accO[s][jd], 0, 0, 0);
                    accO[s][jd] = __builtin_amdgcn_mfma_f32_16x16x32_bf16(ap1, bv1, accO[s][jd], 0, 0, 0);
                }
            }
        }
        // epilogue
#pragma unroll
        for (int s = 0; s < 2; ++s)
#pragma unroll
            for (int r = 0; r < 4; ++r) {
                float inv = 1.0f / lrun[s][r];
#pragma unroll
                for (int jd = 0; jd < 4; ++jd)
                    Ob[(size_t)(b * Ldim + q0 + s * 16 + rowq + r) * Hdim + h * HD + jd * 16 + colq] =
                        f2bf(accO[s][jd][r] * inv);
            }
    }
}

// ---------------- launcher ----------------
extern "C" void kernel_launch(void* const* d_in, const int* in_sizes, int n_in,
                              void* d_out, int out_size, void* d_ws, size_t ws_size,
                              hipStream_t stream) {
    const int*   seqs_data = (const int*)d_in[0];
    const float* seqs      = (const float*)d_in[1];
    const int*   position  = (const int*)d_in[2];
    const float* time_emb  = (const float*)d_in[3];
    const float* pos_table = (const float*)d_in[4];
    const float* gate_W    = (const float*)d_in[5];
    const float* gate_b    = (const float*)d_in[6];
    const float* ln_attn_g = (const float*)d_in[7];
    const float* ln_attn_b = (const float*)d_in[8];
    const float* qW        = (const float*)d_in[9];
    const float* qb        = (const float*)d_in[10];
    const float* kW        = (const float*)d_in[11];
    const float* kb        = (const float*)d_in[12];
    const float* vW        = (const float*)d_in[13];
    const float* vb        = (const float*)d_in[14];
    const float* ln_ffn_g  = (const float*)d_in[15];
    const float* ln_ffn_b  = (const float*)d_in[16];
    const float* c1W       = (const float*)d_in[17];
    const float* c1b       = (const float*)d_in[18];
    const float* c2W       = (const float*)d_in[19];
    const float* c2b       = (const float*)d_in[20];
    const float* last_g    = (const float*)d_in[21];
    const float* last_b    = (const float*)d_in[22];

    size_t BUF = (size_t)NTOK * Hdim;
    float* fws = (float*)d_ws;
    float* GATES = fws;                       // NTOK*2
    float* KEEP  = GATES + (size_t)NTOK * 2;  // NTOK
    unsigned short* bws   = (unsigned short*)(KEEP + NTOK);
    unsigned short* Tbf   = bws;
    unsigned short* QXbf  = Tbf + BUF;        // Q / x / next-Q (in place)
    unsigned short* VINbf = QXbf + BUF;
    unsigned short* HIDbf = VINbf + BUF;
    unsigned short* Qbf   = HIDbf + BUF;
    unsigned short* Kbf   = Qbf + BUF;
    unsigned short* VTbf  = Kbf + BUF;        // V^T [B][NH][HD][L]
    unsigned short* QAbf  = VTbf + BUF;
    unsigned short* Zbf   = QAbf + BUF;       // c2 GEMM output
    unsigned short* Wbf   = Zbf + BUF;
    size_t WB = (size_t)Hdim * Hdim;
    unsigned short* qWbf  = Wbf;
    unsigned short* kWbf  = Wbf + 2 * WB;
    unsigned short* vWbf  = Wbf + 4 * WB;
    unsigned short* c1Wbf = Wbf + 6 * WB;
    unsigned short* c2Wbf = Wbf + 8 * WB;

    castw_kernel<<<dim3(128, 5), 256, 0, stream>>>(qW, kW, vW, c1W, c2W, Wbf);
    prep_ln_kernel<<<NTOK / 4, 256, 0, stream>>>(seqs_data, seqs, position, time_emb,
                                                 pos_table, gate_W, gate_b,
                                                 ln_attn_g, ln_attn_b,
                                                 Tbf, QXbf, VINbf, GATES, KEEP);

    dim3 qkvgrid(Hdim / GBN, NTOK / GBM, 3);   // (2, 256, 3)
    dim3 ggrid(Hdim / GBN, NTOK / GBM);        // (2, 256)
    for (int i = 0; i < 2; ++i) {
        gemm_qkv_kernel<<<qkvgrid, 256, 0, stream>>>(QXbf, Tbf, VINbf,
                                                     qWbf + i * WB, kWbf + i * WB, vWbf + i * WB,
                                                     qb + i * Hdim, kb + i * Hdim, vb + i * Hdim,
                                                     Qbf, Kbf, VTbf);
        attn_mfma_kernel<<<Bdim * NHEAD, 512, ATTN_LDS, stream>>>(Qbf, Kbf, VTbf, GATES, QAbf, i);
        ln2_kernel<<<NTOK / 4, 256, 0, stream>>>(QXbf, QAbf,
                                                 ln_ffn_g + i * Hdim, ln_ffn_b + i * Hdim);
        gemm_plain_kernel<<<ggrid, 256, 0, stream>>>(QXbf, c1Wbf + i * WB, c1b + i * Hdim, HIDbf, 1);
        gemm_plain_kernel<<<ggrid, 256, 0, stream>>>(HIDbf, c2Wbf + i * WB, c2b + i * Hdim, Zbf, 0);
        if (i == 0) {
            lnout_kernel<<<NTOK / 4, 256, 0, stream>>>(
                Zbf, QXbf, Tbf, KEEP,
                ln_attn_g + Hdim, ln_attn_b + Hdim,
                nullptr, VINbf);
        } else {
            lnout_kernel<<<NTOK / 4, 256, 0, stream>>>(
                Zbf, QXbf, Tbf, KEEP,
                last_g, last_b,
                (float*)d_out, nullptr);
        }
    }
}

// Round 11
// 381.245 us; speedup vs baseline: 1.1906x; 1.0069x over previous
//
#include <hip/hip_runtime.h>
#include <hip/hip_bf16.h>
#include <math.h>

// Problem constants
#define NTOK 32768      // B*L = 64*512
#define Hdim 256
#define Ldim 512
#define Bdim 64
#define NHEAD 4
#define HD 64
#define PADV 49999      // ITEMNUM-1

typedef __bf16 bf16x8 __attribute__((ext_vector_type(8)));
typedef __bf16 bf16x4 __attribute__((ext_vector_type(4)));
typedef float  f32x4  __attribute__((ext_vector_type(4)));

union bf8u { bf16x8 v8; bf16x4 v4[2]; };

__device__ __forceinline__ unsigned short f2bf(float f) {
    unsigned int u = __float_as_uint(f);
    unsigned int r = (u + 0x7fffu + ((u >> 16) & 1u)) >> 16;
    return (unsigned short)r;
}
__device__ __forceinline__ float bf2f(unsigned short u) {
    return __uint_as_float(((unsigned int)u) << 16);
}

// async global->LDS, 16B per lane (dest must be wave-uniform base + lane*16)
__device__ __forceinline__ void gload16(const void* g, void* l) {
    __builtin_amdgcn_global_load_lds((const __attribute__((address_space(1))) unsigned int*)g,
                                     (__attribute__((address_space(3))) unsigned int*)l,
                                     16, 0, 0);
}

// ---------------- weight cast: 5 matrices x (2*256*256) f32 -> bf16 ----------------
__global__ __launch_bounds__(256)
void castw_kernel(const float* __restrict__ q, const float* __restrict__ k,
                  const float* __restrict__ v, const float* __restrict__ c1,
                  const float* __restrict__ c2, unsigned short* __restrict__ dst) {
    const float* srcs[5] = {q, k, v, c1, c2};
    const float* s = srcs[blockIdx.y];
    int idx = blockIdx.x * 1024 + threadIdx.x * 4;
    float4 f = *(const float4*)(s + idx);
    unsigned short* d = dst + (size_t)blockIdx.y * 131072 + idx;
    d[0] = f2bf(f.x); d[1] = f2bf(f.y); d[2] = f2bf(f.z); d[3] = f2bf(f.w);
}

// ---------------- prep + ln_attn[0] fused (wave per token), all-bf16 outputs ----------------
__global__ __launch_bounds__(256)
void prep_ln_kernel(const int* __restrict__ seqs_data, const float* __restrict__ seqs,
                    const int* __restrict__ position, const float* __restrict__ time_emb,
                    const float* __restrict__ pos_table, const float* __restrict__ gate_W,
                    const float* __restrict__ gate_b,
                    const float* __restrict__ lnG, const float* __restrict__ lnB,
                    unsigned short* __restrict__ Tbf,
                    unsigned short* __restrict__ QXbf,
                    unsigned short* __restrict__ VINbf,
                    float* __restrict__ gates, float* __restrict__ keepv) {
    int tok  = blockIdx.x * 4 + (threadIdx.x >> 6);
    int lane = threadIdx.x & 63;
    size_t off = (size_t)tok * Hdim + lane * 4;
    int pos = position[tok];
    float4 pe = *(const float4*)(pos_table + (size_t)pos * Hdim + lane * 4);
    float4 sq = *(const float4*)(seqs + off);
    float4 tm = *(const float4*)(time_emb + off);
    float keep = (seqs_data[tok] != PADV) ? 1.0f : 0.0f;
    float4 t = {tm.x + pe.x, tm.y + pe.y, tm.z + pe.z, tm.w + pe.w};
    float4 s = {(sq.x + pe.x) * keep, (sq.y + pe.y) * keep,
                (sq.z + pe.z) * keep, (sq.w + pe.w) * keep};
    ushort4 tb = {f2bf(t.x), f2bf(t.y), f2bf(t.z), f2bf(t.w)};
    *(ushort4*)(Tbf + off) = tb;
    float4 gw0 = *(const float4*)(gate_W + lane * 4);
    float4 gw1 = *(const float4*)(gate_W + Hdim + lane * 4);
    float r0 = s.x + s.y + s.z + s.w;
    float r1 = s.x * s.x + s.y * s.y + s.z * s.z + s.w * s.w;
    float r2 = t.x * gw0.x + t.y * gw0.y + t.z * gw0.z + t.w * gw0.w;
    float r3 = t.x * gw1.x + t.y * gw1.y + t.z * gw1.z + t.w * gw1.w;
#pragma unroll
    for (int o = 1; o < 64; o <<= 1) {
        r0 += __shfl_xor(r0, o, 64);
        r1 += __shfl_xor(r1, o, 64);
        r2 += __shfl_xor(r2, o, 64);
        r3 += __shfl_xor(r3, o, 64);
    }
    float mean = r0 * (1.0f / Hdim);
    float var  = fmaxf(r1 * (1.0f / Hdim) - mean * mean, 0.0f);
    float rstd = rsqrtf(var + 1e-8f);
    if (lane == 0) {
        gates[(size_t)tok * 2 + 0] = 1.0f / (1.0f + __expf(-(r2 + gate_b[0])));
        gates[(size_t)tok * 2 + 1] = 1.0f / (1.0f + __expf(-(r3 + gate_b[1])));
        keepv[tok] = keep;
    }
    float4 g4 = *(const float4*)(lnG + lane * 4);
    float4 b4 = *(const float4*)(lnB + lane * 4);
    float4 y = {(s.x - mean) * rstd * g4.x + b4.x, (s.y - mean) * rstd * g4.y + b4.y,
                (s.z - mean) * rstd * g4.z + b4.z, (s.w - mean) * rstd * g4.w + b4.w};
    ushort4 yb = {f2bf(y.x), f2bf(y.y), f2bf(y.z), f2bf(y.w)};
    *(ushort4*)(QXbf + off) = yb;
    ushort4 vb = {f2bf(s.x + t.x), f2bf(s.y + t.y), f2bf(s.z + t.z), f2bf(s.w + t.w)};
    *(ushort4*)(VINbf + off) = vb;
}

// ---------------- ln_ffn: x = Q(bf16) + QA(bf16); LN -> QXbf in place ----------------
__global__ __launch_bounds__(256)
void ln2_kernel(unsigned short* QXbf, const unsigned short* __restrict__ QA,
                const float* __restrict__ lnG, const float* __restrict__ lnB) {
    int tok  = blockIdx.x * 4 + (threadIdx.x >> 6);
    int lane = threadIdx.x & 63;
    size_t off = (size_t)tok * Hdim + lane * 4;
    ushort4 q = *(const ushort4*)(QXbf + off);
    ushort4 a = *(const ushort4*)(QA + off);
    float4 x = {bf2f(q.x) + bf2f(a.x), bf2f(q.y) + bf2f(a.y),
                bf2f(q.z) + bf2f(a.z), bf2f(q.w) + bf2f(a.w)};
    float r0 = x.x + x.y + x.z + x.w;
    float r1 = x.x * x.x + x.y * x.y + x.z * x.z + x.w * x.w;
#pragma unroll
    for (int o = 1; o < 64; o <<= 1) {
        r0 += __shfl_xor(r0, o, 64);
        r1 += __shfl_xor(r1, o, 64);
    }
    float mean = r0 * (1.0f / Hdim);
    float var  = fmaxf(r1 * (1.0f / Hdim) - mean * mean, 0.0f);
    float rstd = rsqrtf(var + 1e-8f);
    float4 g4 = *(const float4*)(lnG + lane * 4);
    float4 b4 = *(const float4*)(lnB + lane * 4);
    ushort4 yb = {f2bf((x.x - mean) * rstd * g4.x + b4.x),
                  f2bf((x.y - mean) * rstd * g4.y + b4.y),
                  f2bf((x.z - mean) * rstd * g4.z + b4.z),
                  f2bf((x.w - mean) * rstd * g4.w + b4.w)};
    *(ushort4*)(QXbf + off) = yb;
}

// ---------------- lnout: S=(Z+x)*keep; LN -> next-Q/VIN (i=0) or d_out f32 (i=1) ----------------
__global__ __launch_bounds__(256)
void lnout_kernel(const unsigned short* __restrict__ Zbf,
                  unsigned short* QXbf,
                  const unsigned short* __restrict__ Tbf,
                  const float* __restrict__ keepv,
                  const float* __restrict__ lnG, const float* __restrict__ lnB,
                  float* __restrict__ outF,
                  unsigned short* __restrict__ outVIN) {
    int tok  = blockIdx.x * 4 + (threadIdx.x >> 6);
    int lane = threadIdx.x & 63;
    size_t off = (size_t)tok * Hdim + lane * 4;
    ushort4 z = *(const ushort4*)(Zbf + off);
    ushort4 x = *(const ushort4*)(QXbf + off);
    float kf = keepv[tok];
    float4 s = {(bf2f(z.x) + bf2f(x.x)) * kf, (bf2f(z.y) + bf2f(x.y)) * kf,
                (bf2f(z.z) + bf2f(x.z)) * kf, (bf2f(z.w) + bf2f(x.w)) * kf};
    float r0 = s.x + s.y + s.z + s.w;
    float r1 = s.x * s.x + s.y * s.y + s.z * s.z + s.w * s.w;
#pragma unroll
    for (int o = 1; o < 64; o <<= 1) {
        r0 += __shfl_xor(r0, o, 64);
        r1 += __shfl_xor(r1, o, 64);
    }
    float mean = r0 * (1.0f / Hdim);
    float var  = fmaxf(r1 * (1.0f / Hdim) - mean * mean, 0.0f);
    float rstd = rsqrtf(var + 1e-8f);
    float4 g4 = *(const float4*)(lnG + lane * 4);
    float4 b4 = *(const float4*)(lnB + lane * 4);
    float4 y = {(s.x - mean) * rstd * g4.x + b4.x, (s.y - mean) * rstd * g4.y + b4.y,
                (s.z - mean) * rstd * g4.z + b4.z, (s.w - mean) * rstd * g4.w + b4.w};
    if (outF) {
        *(float4*)(outF + off) = y;
    } else {
        ushort4 yb = {f2bf(y.x), f2bf(y.y), f2bf(y.z), f2bf(y.w)};
        *(ushort4*)(QXbf + off) = yb;
        ushort4 t = *(const ushort4*)(Tbf + off);
        ushort4 vb = {f2bf(s.x + bf2f(t.x)), f2bf(s.y + bf2f(t.y)),
                      f2bf(s.z + bf2f(t.z)), f2bf(s.w + bf2f(t.w))};
        *(ushort4*)(outVIN + off) = vb;
    }
}

#define GBM 128
#define GBN 128
#define GBK 32

// ---------------- merged q/k/v GEMM 128x128: blockIdx.z selects operand set ----------------
__global__ __launch_bounds__(256)
void gemm_qkv_kernel(const unsigned short* __restrict__ QXbf,
                     const unsigned short* __restrict__ Tbf,
                     const unsigned short* __restrict__ VINbf,
                     const unsigned short* __restrict__ qW,
                     const unsigned short* __restrict__ kW,
                     const unsigned short* __restrict__ vW,
                     const float* __restrict__ qb, const float* __restrict__ kb,
                     const float* __restrict__ vb,
                     unsigned short* __restrict__ Qbf,
                     unsigned short* __restrict__ Kbf,
                     unsigned short* __restrict__ VT) {
    __shared__ __align__(16) char smem[128 * 136 * 2];
    __bf16 (*As)[GBK] = (__bf16 (*)[GBK])smem;
    __bf16 (*Ws)[GBK] = (__bf16 (*)[GBK])(smem + 8192);
    __bf16 (*Ct)[136] = (__bf16 (*)[136])smem;
    int z = blockIdx.z;
    const unsigned short* A = (z == 0) ? QXbf : (z == 1) ? Tbf : VINbf;
    const unsigned short* W = (z == 0) ? qW : (z == 1) ? kW : vW;
    const float* bias       = (z == 0) ? qb : (z == 1) ? kb : vb;

    int tid = threadIdx.x, lane = tid & 63, w = tid >> 6;
    int wr = w >> 1, wc = w & 1;
    int m0 = blockIdx.y * GBM, n0 = blockIdx.x * GBN;
    f32x4 acc[4][4];
#pragma unroll
    for (int i = 0; i < 4; ++i)
#pragma unroll
        for (int j = 0; j < 4; ++j) acc[i][j] = (f32x4)(0.0f);
    int cA = tid, cB = tid + 256;
    int rA = cA >> 2, kA = (cA & 3) * 8;
    int rB = cB >> 2, kB = (cB & 3) * 8;
    int colq = lane & 15, kq = (lane >> 4) * 8;
    for (int kc = 0; kc < Hdim; kc += GBK) {
        __syncthreads();
        gload16(A + (size_t)(m0 + rA) * Hdim + kc + kA, (__bf16*)As + cA * 8);
        gload16(A + (size_t)(m0 + rB) * Hdim + kc + kB, (__bf16*)As + cB * 8);
        gload16(W + (size_t)(n0 + rA) * Hdim + kc + kA, (__bf16*)Ws + cA * 8);
        gload16(W + (size_t)(n0 + rB) * Hdim + kc + kB, (__bf16*)Ws + cB * 8);
        __syncthreads();
        bf16x8 af[4], bfr[4];
#pragma unroll
        for (int i = 0; i < 4; ++i)
            af[i] = *(const bf16x8*)&As[wr * 64 + i * 16 + colq][kq];
#pragma unroll
        for (int j = 0; j < 4; ++j)
            bfr[j] = *(const bf16x8*)&Ws[wc * 64 + j * 16 + colq][kq];
#pragma unroll
        for (int i = 0; i < 4; ++i)
#pragma unroll
            for (int j = 0; j < 4; ++j)
                acc[i][j] = __builtin_amdgcn_mfma_f32_16x16x32_bf16(af[i], bfr[j], acc[i][j], 0, 0, 0);
    }
    int rowq = (lane >> 4) * 4;
    if (z < 2) {
        unsigned short* outBF = (z == 0) ? Qbf : Kbf;
#pragma unroll
        for (int i = 0; i < 4; ++i)
#pragma unroll
            for (int r = 0; r < 4; ++r) {
                int m = m0 + wr * 64 + i * 16 + rowq + r;
#pragma unroll
                for (int j = 0; j < 4; ++j) {
                    int n = n0 + wc * 64 + j * 16 + colq;
                    outBF[(size_t)m * Hdim + n] = f2bf(acc[i][j][r] + bias[n]);
                }
            }
    } else {
        __syncthreads();
#pragma unroll
        for (int i = 0; i < 4; ++i)
#pragma unroll
            for (int r = 0; r < 4; ++r) {
                int ml = wr * 64 + i * 16 + rowq + r;
#pragma unroll
                for (int j = 0; j < 4; ++j) {
                    int nl = wc * 64 + j * 16 + colq;
                    Ct[nl][ml] = (__bf16)(acc[i][j][r] + bias[n0 + nl]);
                }
            }
        __syncthreads();
        int bb = m0 >> 9, l0 = m0 & 511;
#pragma unroll
        for (int it = 0; it < 8; ++it) {
            int c = tid + it * 256;
            int nl = c >> 4;
            int o8 = (c & 15) * 8;
            int n = n0 + nl;
            int hh = n >> 6, dd = n & 63;
            bf16x8 v = *(const bf16x8*)&Ct[nl][o8];
            *(bf16x8*)(VT + ((((size_t)bb * NHEAD + hh) * HD + dd) * Ldim + l0 + o8)) = v;
        }
    }
}

// ---------------- plain bf16 GEMM 128x128: C = A@W^T + bias [relu] -> bf16 ----------------
__global__ __launch_bounds__(256)
void gemm_plain_kernel(const unsigned short* __restrict__ A,
                       const unsigned short* __restrict__ W,
                       const float* __restrict__ bias,
                       unsigned short* __restrict__ outBF, int doRelu) {
    __shared__ __bf16 As[GBM][GBK];
    __shared__ __bf16 Ws[GBN][GBK];
    int tid = threadIdx.x, lane = tid & 63, w = tid >> 6;
    int wr = w >> 1, wc = w & 1;
    int m0 = blockIdx.y * GBM, n0 = blockIdx.x * GBN;
    f32x4 acc[4][4];
#pragma unroll
    for (int i = 0; i < 4; ++i)
#pragma unroll
        for (int j = 0; j < 4; ++j) acc[i][j] = (f32x4)(0.0f);
    int cA = tid, cB = tid + 256;
    int rA = cA >> 2, kA = (cA & 3) * 8;
    int rB = cB >> 2, kB = (cB & 3) * 8;
    int colq = lane & 15, kq = (lane >> 4) * 8;
    for (int kc = 0; kc < Hdim; kc += GBK) {
        __syncthreads();
        gload16(A + (size_t)(m0 + rA) * Hdim + kc + kA, (__bf16*)As + cA * 8);
        gload16(A + (size_t)(m0 + rB) * Hdim + kc + kB, (__bf16*)As + cB * 8);
        gload16(W + (size_t)(n0 + rA) * Hdim + kc + kA, (__bf16*)Ws + cA * 8);
        gload16(W + (size_t)(n0 + rB) * Hdim + kc + kB, (__bf16*)Ws + cB * 8);
        __syncthreads();
        bf16x8 af[4], bfr[4];
#pragma unroll
        for (int i = 0; i < 4; ++i)
            af[i] = *(const bf16x8*)&As[wr * 64 + i * 16 + colq][kq];
#pragma unroll
        for (int j = 0; j < 4; ++j)
            bfr[j] = *(const bf16x8*)&Ws[wc * 64 + j * 16 + colq][kq];
#pragma unroll
        for (int i = 0; i < 4; ++i)
#pragma unroll
            for (int j = 0; j < 4; ++j)
                acc[i][j] = __builtin_amdgcn_mfma_f32_16x16x32_bf16(af[i], bfr[j], acc[i][j], 0, 0, 0);
    }
    int rowq = (lane >> 4) * 4;
#pragma unroll
    for (int i = 0; i < 4; ++i)
#pragma unroll
        for (int r = 0; r < 4; ++r) {
            int m = m0 + wr * 64 + i * 16 + rowq + r;
#pragma unroll
            for (int j = 0; j < 4; ++j) {
                int n = n0 + wc * 64 + j * 16 + colq;
                float v = acc[i][j][r] + bias[n];
                if (doRelu) v = fmaxf(v, 0.0f);
                outBF[(size_t)m * Hdim + n] = f2bf(v);
            }
        }
}

// ---------------- persistent per-(b,h) attention, 12 waves, b64-aligned slim strides ----------------
// 256 blocks x 768 threads (12 waves = 3/SIMD). LDS:
//   K[512][68]  = 69632 B   (stride 136 B: b64-aligned, 2-way banks = free)
//   VT[64][516] = 66048 B   (stride 1032 B)
//   P[192][68]  = 26112 B   (wave-private 16-row strips)
//   total 161792 B (<160 KiB)
// Work: 32 granules of 16 q-rows; cost(g)=g/4+1; waves get {1,3,8}/{2,4,6}/{5,7} = 12 units each.
// Single barrier after K/VT staging; everything after is wave-autonomous.
#define AKS 68
#define AVS 516
#define APS 68
#define ATTN_LDS (512 * AKS * 2 + 64 * AVS * 2 + 192 * APS * 2)
__global__ __launch_bounds__(768, 1)
void attn_mfma_kernel(const unsigned short* __restrict__ Qg,
                      const unsigned short* __restrict__ Kg,
                      const unsigned short* __restrict__ VTg,
                      const float* __restrict__ gates,
                      unsigned short* __restrict__ Ob, int blk) {
    extern __shared__ __align__(16) char smem[];
    __bf16 (*Ks)[AKS]  = (__bf16 (*)[AKS])smem;
    __bf16 (*VTs)[AVS] = (__bf16 (*)[AVS])(smem + 512 * AKS * 2);
    __bf16 (*Ps)[APS]  = (__bf16 (*)[APS])(smem + 512 * AKS * 2 + 64 * AVS * 2);
    int h = blockIdx.x & 3, b = blockIdx.x >> 2;
    int tid = threadIdx.x, lane = tid & 63, w = tid >> 6;
    int colq = lane & 15, grp = lane >> 4;
    int rowq = grp * 4, kq = grp * 8;

    // stage K (512x64) and V^T (64x512); b64 writes (rows only 8B-aligned)
    size_t baseK = (size_t)b * Ldim * Hdim + h * HD;
    for (int c = tid; c < 4096; c += 768) {
        int r = c >> 3, o = (c & 7) * 8;
        bf8u u;
        u.v8 = *(const bf16x8*)(Kg + baseK + (size_t)r * Hdim + o);
        *(bf16x4*)&Ks[r][o]     = u.v4[0];
        *(bf16x4*)&Ks[r][o + 4] = u.v4[1];
    }
    size_t baseV = ((size_t)b * NHEAD + h) * HD * Ldim;
    for (int c = tid; c < 4096; c += 768) {
        int d = c >> 6, k = (c & 63) * 8;
        bf8u u;
        u.v8 = *(const bf16x8*)(VTg + baseV + (size_t)d * Ldim + k);
        *(bf16x4*)&VTs[d][k]     = u.v4[0];
        *(bf16x4*)&VTs[d][k + 4] = u.v4[1];
    }
    __syncthreads();   // the ONLY barrier

    const float lscale = 0.125f * 1.44269504f;
    // granule assignment (16-row granules, causal-cost-balanced: 12 units/wave)
    int gl[3], ng;
    if (w < 4)      { gl[0] = w;     gl[1] = 8 + w;  gl[2] = 28 + w; ng = 3; }
    else if (w < 8) { gl[0] = w;     gl[1] = 8 + w;  gl[2] = 16 + w; ng = 3; }
    else            { gl[0] = 8 + w; gl[1] = 16 + w; gl[2] = 0;      ng = 2; }

    for (int gi = 0; gi < ng; ++gi) {
        int g = gl[gi];
        int q0 = g * 16;
        // Q fragments from global (registers only)
        size_t qrow = (size_t)(b * Ldim + q0 + colq) * Hdim + h * HD;
        bf16x8 afq0 = *(const bf16x8*)(Qg + qrow + kq);
        bf16x8 afq1 = *(const bf16x8*)(Qg + qrow + 32 + kq);
        float gql[4];
#pragma unroll
        for (int r = 0; r < 4; ++r)
            gql[r] = gates[((size_t)b * Ldim + q0 + rowq + r) * 2 + blk] * lscale;

        float lrun[4] = {0.0f, 0.0f, 0.0f, 0.0f};
        f32x4 accO[4];
#pragma unroll
        for (int jd = 0; jd < 4; ++jd) accO[jd] = (f32x4)(0.0f);

        int nfull = g >> 2;   // kt tiles 0..nfull, nfull is the diagonal tile
        for (int kt = 0; kt <= nfull; ++kt) {
            int k0 = kt * 64;
            bool diag = (kt == nfull);
            // S = Q K^T
            f32x4 sv[4];
#pragma unroll
            for (int j = 0; j < 4; ++j) sv[j] = (f32x4)(0.0f);
#pragma unroll
            for (int j = 0; j < 4; ++j) {
                int kr = k0 + j * 16 + colq;
                bf8u b0, b1;
                b0.v4[0] = *(const bf16x4*)&Ks[kr][kq];
                b0.v4[1] = *(const bf16x4*)&Ks[kr][kq + 4];
                b1.v4[0] = *(const bf16x4*)&Ks[kr][32 + kq];
                b1.v4[1] = *(const bf16x4*)&Ks[kr][32 + kq + 4];
                sv[j] = __builtin_amdgcn_mfma_f32_16x16x32_bf16(afq0, b0.v8, sv[j], 0, 0, 0);
                sv[j] = __builtin_amdgcn_mfma_f32_16x16x32_bf16(afq1, b1.v8, sv[j], 0, 0, 0);
            }
            float gkv[4];
#pragma unroll
            for (int j = 0; j < 4; ++j)
                gkv[j] = gates[((size_t)b * Ldim + k0 + j * 16 + colq) * 2 + blk];

            // unshifted exp2 softmax; mask only on the diagonal tile
#pragma unroll
            for (int r = 0; r < 4; ++r) {
                float su = 0.0f;
                float p4[4];
                if (diag) {
                    int qg = q0 + rowq + r;
#pragma unroll
                    for (int j = 0; j < 4; ++j) {
                        float v = sv[j][r] * gql[r] * gkv[j];
                        v = (k0 + j * 16 + colq > qg) ? -1e38f : v;
                        float e = exp2f(v);
                        p4[j] = e;
                        su += e;
                    }
                } else {
#pragma unroll
                    for (int j = 0; j < 4; ++j) {
                        float e = exp2f(sv[j][r] * gql[r] * gkv[j]);
                        p4[j] = e;
                        su += e;
                    }
                }
#pragma unroll
                for (int off = 1; off < 16; off <<= 1)
                    su += __shfl_xor(su, off, 16);
                lrun[r] += su;
#pragma unroll
                for (int j = 0; j < 4; ++j)
                    Ps[w * 16 + rowq + r][j * 16 + colq] = (__bf16)p4[j];
            }

            // O += P V (wave-private strip, within-wave LDS FIFO, no barrier)
            bf8u a0, a1;
            a0.v4[0] = *(const bf16x4*)&Ps[w * 16 + colq][kq];
            a0.v4[1] = *(const bf16x4*)&Ps[w * 16 + colq][kq + 4];
            a1.v4[0] = *(const bf16x4*)&Ps[w * 16 + colq][32 + kq];
            a1.v4[1] = *(const bf16x4*)&Ps[w * 16 + colq][32 + kq + 4];
#pragma unroll
            for (int jd = 0; jd < 4; ++jd) {
                int vr = jd * 16 + colq;
                bf8u v0, v1;
                v0.v4[0] = *(const bf16x4*)&VTs[vr][k0 + kq];
                v0.v4[1] = *(const bf16x4*)&VTs[vr][k0 + kq + 4];
                v1.v4[0] = *(const bf16x4*)&VTs[vr][k0 + 32 + kq];
                v1.v4[1] = *(const bf16x4*)&VTs[vr][k0 + 32 + kq + 4];
                accO[jd] = __builtin_amdgcn_mfma_f32_16x16x32_bf16(a0.v8, v0.v8, accO[jd], 0, 0, 0);
                accO[jd] = __builtin_amdgcn_mfma_f32_16x16x32_bf16(a1.v8, v1.v8, accO[jd], 0, 0, 0);
            }
        }
        // epilogue for this granule
#pragma unroll
        for (int r = 0; r < 4; ++r) {
            float inv = 1.0f / lrun[r];
#pragma unroll
            for (int jd = 0; jd < 4; ++jd)
                Ob[(size_t)(b * Ldim + q0 + rowq + r) * Hdim + h * HD + jd * 16 + colq] =
                    f2bf(accO[jd][r] * inv);
        }
    }
}

// ---------------- launcher ----------------
extern "C" void kernel_launch(void* const* d_in, const int* in_sizes, int n_in,
                              void* d_out, int out_size, void* d_ws, size_t ws_size,
                              hipStream_t stream) {
    const int*   seqs_data = (const int*)d_in[0];
    const float* seqs      = (const float*)d_in[1];
    const int*   position  = (const int*)d_in[2];
    const float* time_emb  = (const float*)d_in[3];
    const float* pos_table = (const float*)d_in[4];
    const float* gate_W    = (const float*)d_in[5];
    const float* gate_b    = (const float*)d_in[6];
    const float* ln_attn_g = (const float*)d_in[7];
    const float* ln_attn_b = (const float*)d_in[8];
    const float* qW        = (const float*)d_in[9];
    const float* qb        = (const float*)d_in[10];
    const float* kW        = (const float*)d_in[11];
    const float* kb        = (const float*)d_in[12];
    const float* vW        = (const float*)d_in[13];
    const float* vb        = (const float*)d_in[14];
    const float* ln_ffn_g  = (const float*)d_in[15];
    const float* ln_ffn_b  = (const float*)d_in[16];
    const float* c1W       = (const float*)d_in[17];
    const float* c1b       = (const float*)d_in[18];
    const float* c2W       = (const float*)d_in[19];
    const float* c2b       = (const float*)d_in[20];
    const float* last_g    = (const float*)d_in[21];
    const float* last_b    = (const float*)d_in[22];

    size_t BUF = (size_t)NTOK * Hdim;
    float* fws = (float*)d_ws;
    float* GATES = fws;                       // NTOK*2
    float* KEEP  = GATES + (size_t)NTOK * 2;  // NTOK
    unsigned short* bws   = (unsigned short*)(KEEP + NTOK);
    unsigned short* Tbf   = bws;
    unsigned short* QXbf  = Tbf + BUF;        // Q / x / next-Q (in place)
    unsigned short* VINbf = QXbf + BUF;
    unsigned short* HIDbf = VINbf + BUF;
    unsigned short* Qbf   = HIDbf + BUF;
    unsigned short* Kbf   = Qbf + BUF;
    unsigned short* VTbf  = Kbf + BUF;        // V^T [B][NH][HD][L]
    unsigned short* QAbf  = VTbf + BUF;
    unsigned short* Zbf   = QAbf + BUF;       // c2 GEMM output
    unsigned short* Wbf   = Zbf + BUF;
    size_t WB = (size_t)Hdim * Hdim;
    unsigned short* qWbf  = Wbf;
    unsigned short* kWbf  = Wbf + 2 * WB;
    unsigned short* vWbf  = Wbf + 4 * WB;
    unsigned short* c1Wbf = Wbf + 6 * WB;
    unsigned short* c2Wbf = Wbf + 8 * WB;

    castw_kernel<<<dim3(128, 5), 256, 0, stream>>>(qW, kW, vW, c1W, c2W, Wbf);
    prep_ln_kernel<<<NTOK / 4, 256, 0, stream>>>(seqs_data, seqs, position, time_emb,
                                                 pos_table, gate_W, gate_b,
                                                 ln_attn_g, ln_attn_b,
                                                 Tbf, QXbf, VINbf, GATES, KEEP);

    dim3 qkvgrid(Hdim / GBN, NTOK / GBM, 3);   // (2, 256, 3)
    dim3 ggrid(Hdim / GBN, NTOK / GBM);        // (2, 256)
    for (int i = 0; i < 2; ++i) {
        gemm_qkv_kernel<<<qkvgrid, 256, 0, stream>>>(QXbf, Tbf, VINbf,
                                                     qWbf + i * WB, kWbf + i * WB, vWbf + i * WB,
                                                     qb + i * Hdim, kb + i * Hdim, vb + i * Hdim,
                                                     Qbf, Kbf, VTbf);
        attn_mfma_kernel<<<Bdim * NHEAD, 768, ATTN_LDS, stream>>>(Qbf, Kbf, VTbf, GATES, QAbf, i);
        ln2_kernel<<<NTOK / 4, 256, 0, stream>>>(QXbf, QAbf,
                                                 ln_ffn_g + i * Hdim, ln_ffn_b + i * Hdim);
        gemm_plain_kernel<<<ggrid, 256, 0, stream>>>(QXbf, c1Wbf + i * WB, c1b + i * Hdim, HIDbf, 1);
        gemm_plain_kernel<<<ggrid, 256, 0, stream>>>(HIDbf, c2Wbf + i * WB, c2b + i * Hdim, Zbf, 0);
        if (i == 0) {
            lnout_kernel<<<NTOK / 4, 256, 0, stream>>>(
                Zbf, QXbf, Tbf, KEEP,
                ln_attn_g + Hdim, ln_attn_b + Hdim,
                nullptr, VINbf);
        } else {
            lnout_kernel<<<NTOK / 4, 256, 0, stream>>>(
                Zbf, QXbf, Tbf, KEEP,
                last_g, last_b,
                (float*)d_out, nullptr);
        }
    }
}

// Round 12
// 377.674 us; speedup vs baseline: 1.2018x; 1.0095x over previous
//
#include <hip/hip_runtime.h>
#include <hip/hip_bf16.h>
#include <math.h>

// Problem constants
#define NTOK 32768      // B*L = 64*512
#define Hdim 256
#define Ldim 512
#define Bdim 64
#define NHEAD 4
#define HD 64
#define PADV 49999      // ITEMNUM-1

typedef __bf16 bf16x8 __attribute__((ext_vector_type(8)));
typedef __bf16 bf16x4 __attribute__((ext_vector_type(4)));
typedef float  f32x4  __attribute__((ext_vector_type(4)));

union bf8u { bf16x8 v8; bf16x4 v4[2]; };

__device__ __forceinline__ unsigned short f2bf(float f) {
    unsigned int u = __float_as_uint(f);
    unsigned int r = (u + 0x7fffu + ((u >> 16) & 1u)) >> 16;
    return (unsigned short)r;
}
__device__ __forceinline__ float bf2f(unsigned short u) {
    return __uint_as_float(((unsigned int)u) << 16);
}

// async global->LDS, 16B per lane (dest must be wave-uniform base + lane*16)
__device__ __forceinline__ void gload16(const void* g, void* l) {
    __builtin_amdgcn_global_load_lds((const __attribute__((address_space(1))) unsigned int*)g,
                                     (__attribute__((address_space(3))) unsigned int*)l,
                                     16, 0, 0);
}

// ---------------- weight cast: 5 matrices x (2*256*256) f32 -> bf16 ----------------
__global__ __launch_bounds__(256)
void castw_kernel(const float* __restrict__ q, const float* __restrict__ k,
                  const float* __restrict__ v, const float* __restrict__ c1,
                  const float* __restrict__ c2, unsigned short* __restrict__ dst) {
    const float* srcs[5] = {q, k, v, c1, c2};
    const float* s = srcs[blockIdx.y];
    int idx = blockIdx.x * 1024 + threadIdx.x * 4;
    float4 f = *(const float4*)(s + idx);
    unsigned short* d = dst + (size_t)blockIdx.y * 131072 + idx;
    d[0] = f2bf(f.x); d[1] = f2bf(f.y); d[2] = f2bf(f.z); d[3] = f2bf(f.w);
}

// ---------------- prep + ln_attn[0] fused (wave per token), all-bf16 outputs ----------------
__global__ __launch_bounds__(256)
void prep_ln_kernel(const int* __restrict__ seqs_data, const float* __restrict__ seqs,
                    const int* __restrict__ position, const float* __restrict__ time_emb,
                    const float* __restrict__ pos_table, const float* __restrict__ gate_W,
                    const float* __restrict__ gate_b,
                    const float* __restrict__ lnG, const float* __restrict__ lnB,
                    unsigned short* __restrict__ Tbf,
                    unsigned short* __restrict__ QXbf,
                    unsigned short* __restrict__ VINbf,
                    float* __restrict__ gates, float* __restrict__ keepv) {
    int tok  = blockIdx.x * 4 + (threadIdx.x >> 6);
    int lane = threadIdx.x & 63;
    size_t off = (size_t)tok * Hdim + lane * 4;
    int pos = position[tok];
    float4 pe = *(const float4*)(pos_table + (size_t)pos * Hdim + lane * 4);
    float4 sq = *(const float4*)(seqs + off);
    float4 tm = *(const float4*)(time_emb + off);
    float keep = (seqs_data[tok] != PADV) ? 1.0f : 0.0f;
    float4 t = {tm.x + pe.x, tm.y + pe.y, tm.z + pe.z, tm.w + pe.w};
    float4 s = {(sq.x + pe.x) * keep, (sq.y + pe.y) * keep,
                (sq.z + pe.z) * keep, (sq.w + pe.w) * keep};
    ushort4 tb = {f2bf(t.x), f2bf(t.y), f2bf(t.z), f2bf(t.w)};
    *(ushort4*)(Tbf + off) = tb;
    float4 gw0 = *(const float4*)(gate_W + lane * 4);
    float4 gw1 = *(const float4*)(gate_W + Hdim + lane * 4);
    float r0 = s.x + s.y + s.z + s.w;
    float r1 = s.x * s.x + s.y * s.y + s.z * s.z + s.w * s.w;
    float r2 = t.x * gw0.x + t.y * gw0.y + t.z * gw0.z + t.w * gw0.w;
    float r3 = t.x * gw1.x + t.y * gw1.y + t.z * gw1.z + t.w * gw1.w;
#pragma unroll
    for (int o = 1; o < 64; o <<= 1) {
        r0 += __shfl_xor(r0, o, 64);
        r1 += __shfl_xor(r1, o, 64);
        r2 += __shfl_xor(r2, o, 64);
        r3 += __shfl_xor(r3, o, 64);
    }
    float mean = r0 * (1.0f / Hdim);
    float var  = fmaxf(r1 * (1.0f / Hdim) - mean * mean, 0.0f);
    float rstd = rsqrtf(var + 1e-8f);
    if (lane == 0) {
        gates[(size_t)tok * 2 + 0] = 1.0f / (1.0f + __expf(-(r2 + gate_b[0])));
        gates[(size_t)tok * 2 + 1] = 1.0f / (1.0f + __expf(-(r3 + gate_b[1])));
        keepv[tok] = keep;
    }
    float4 g4 = *(const float4*)(lnG + lane * 4);
    float4 b4 = *(const float4*)(lnB + lane * 4);
    float4 y = {(s.x - mean) * rstd * g4.x + b4.x, (s.y - mean) * rstd * g4.y + b4.y,
                (s.z - mean) * rstd * g4.z + b4.z, (s.w - mean) * rstd * g4.w + b4.w};
    ushort4 yb = {f2bf(y.x), f2bf(y.y), f2bf(y.z), f2bf(y.w)};
    *(ushort4*)(QXbf + off) = yb;
    ushort4 vb = {f2bf(s.x + t.x), f2bf(s.y + t.y), f2bf(s.z + t.z), f2bf(s.w + t.w)};
    *(ushort4*)(VINbf + off) = vb;
}

// ---------------- ln_ffn: x = Q(bf16) + QA(bf16); LN -> QXbf in place ----------------
__global__ __launch_bounds__(256)
void ln2_kernel(unsigned short* QXbf, const unsigned short* __restrict__ QA,
                const float* __restrict__ lnG, const float* __restrict__ lnB) {
    int tok  = blockIdx.x * 4 + (threadIdx.x >> 6);
    int lane = threadIdx.x & 63;
    size_t off = (size_t)tok * Hdim + lane * 4;
    ushort4 q = *(const ushort4*)(QXbf + off);
    ushort4 a = *(const ushort4*)(QA + off);
    float4 x = {bf2f(q.x) + bf2f(a.x), bf2f(q.y) + bf2f(a.y),
                bf2f(q.z) + bf2f(a.z), bf2f(q.w) + bf2f(a.w)};
    float r0 = x.x + x.y + x.z + x.w;
    float r1 = x.x * x.x + x.y * x.y + x.z * x.z + x.w * x.w;
#pragma unroll
    for (int o = 1; o < 64; o <<= 1) {
        r0 += __shfl_xor(r0, o, 64);
        r1 += __shfl_xor(r1, o, 64);
    }
    float mean = r0 * (1.0f / Hdim);
    float var  = fmaxf(r1 * (1.0f / Hdim) - mean * mean, 0.0f);
    float rstd = rsqrtf(var + 1e-8f);
    float4 g4 = *(const float4*)(lnG + lane * 4);
    float4 b4 = *(const float4*)(lnB + lane * 4);
    ushort4 yb = {f2bf((x.x - mean) * rstd * g4.x + b4.x),
                  f2bf((x.y - mean) * rstd * g4.y + b4.y),
                  f2bf((x.z - mean) * rstd * g4.z + b4.z),
                  f2bf((x.w - mean) * rstd * g4.w + b4.w)};
    *(ushort4*)(QXbf + off) = yb;
}

// ---------------- lnout: S=(Z+x)*keep; LN -> next-Q/VIN (i=0) or d_out f32 (i=1) ----------------
__global__ __launch_bounds__(256)
void lnout_kernel(const unsigned short* __restrict__ Zbf,
                  unsigned short* QXbf,
                  const unsigned short* __restrict__ Tbf,
                  const float* __restrict__ keepv,
                  const float* __restrict__ lnG, const float* __restrict__ lnB,
                  float* __restrict__ outF,
                  unsigned short* __restrict__ outVIN) {
    int tok  = blockIdx.x * 4 + (threadIdx.x >> 6);
    int lane = threadIdx.x & 63;
    size_t off = (size_t)tok * Hdim + lane * 4;
    ushort4 z = *(const ushort4*)(Zbf + off);
    ushort4 x = *(const ushort4*)(QXbf + off);
    float kf = keepv[tok];
    float4 s = {(bf2f(z.x) + bf2f(x.x)) * kf, (bf2f(z.y) + bf2f(x.y)) * kf,
                (bf2f(z.z) + bf2f(x.z)) * kf, (bf2f(z.w) + bf2f(x.w)) * kf};
    float r0 = s.x + s.y + s.z + s.w;
    float r1 = s.x * s.x + s.y * s.y + s.z * s.z + s.w * s.w;
#pragma unroll
    for (int o = 1; o < 64; o <<= 1) {
        r0 += __shfl_xor(r0, o, 64);
        r1 += __shfl_xor(r1, o, 64);
    }
    float mean = r0 * (1.0f / Hdim);
    float var  = fmaxf(r1 * (1.0f / Hdim) - mean * mean, 0.0f);
    float rstd = rsqrtf(var + 1e-8f);
    float4 g4 = *(const float4*)(lnG + lane * 4);
    float4 b4 = *(const float4*)(lnB + lane * 4);
    float4 y = {(s.x - mean) * rstd * g4.x + b4.x, (s.y - mean) * rstd * g4.y + b4.y,
                (s.z - mean) * rstd * g4.z + b4.z, (s.w - mean) * rstd * g4.w + b4.w};
    if (outF) {
        *(float4*)(outF + off) = y;
    } else {
        ushort4 yb = {f2bf(y.x), f2bf(y.y), f2bf(y.z), f2bf(y.w)};
        *(ushort4*)(QXbf + off) = yb;
        ushort4 t = *(const ushort4*)(Tbf + off);
        ushort4 vb = {f2bf(s.x + bf2f(t.x)), f2bf(s.y + bf2f(t.y)),
                      f2bf(s.z + bf2f(t.z)), f2bf(s.w + bf2f(t.w))};
        *(ushort4*)(outVIN + off) = vb;
    }
}

#define GBM 128
#define GBN 128
#define GBK 64

// staging with XOR-swizzled chunk mapping: LDS is linear (gload16 requirement);
// lane fetches global chunk (row=c>>3, col8 = (c&7) ^ (row&7)); frag reads at
// row r, col-group g live at slot g^(r&7) -> 16-lane frag reads spread across
// all 8 chunk slots = conflict-free (2-way only).
__device__ __forceinline__ void stage64(const unsigned short* __restrict__ src,
                                        size_t rowBase, __bf16* lds, int tid, int kc) {
#pragma unroll
    for (int it = 0; it < 4; ++it) {
        int c = tid + it * 256;
        int r = c >> 3, sub = c & 7;
        int g = sub ^ (r & 7);
        gload16(src + (rowBase + r) * Hdim + kc + g * 8, lds + c * 8);
    }
}
__device__ __forceinline__ bf16x8 frag64(const __bf16* lds, int r, int g) {
    return *(const bf16x8*)(lds + r * 64 + (g ^ (r & 7)) * 8);
}

// ---------------- merged q/k/v GEMM 128x128 BK=64: blockIdx.z selects operand set ----------------
__global__ __launch_bounds__(256)
void gemm_qkv_kernel(const unsigned short* __restrict__ QXbf,
                     const unsigned short* __restrict__ Tbf,
                     const unsigned short* __restrict__ VINbf,
                     const unsigned short* __restrict__ qW,
                     const unsigned short* __restrict__ kW,
                     const unsigned short* __restrict__ vW,
                     const float* __restrict__ qb, const float* __restrict__ kb,
                     const float* __restrict__ vb,
                     unsigned short* __restrict__ Qbf,
                     unsigned short* __restrict__ Kbf,
                     unsigned short* __restrict__ VT) {
    // As(16K)+Ws(16K) = 32K, union with Ct[128][136] = 34816
    __shared__ __align__(16) char smem[128 * 136 * 2];
    __bf16* As = (__bf16*)smem;
    __bf16* Ws = (__bf16*)(smem + 16384);
    __bf16 (*Ct)[136] = (__bf16 (*)[136])smem;
    int z = blockIdx.z;
    const unsigned short* A = (z == 0) ? QXbf : (z == 1) ? Tbf : VINbf;
    const unsigned short* W = (z == 0) ? qW : (z == 1) ? kW : vW;
    const float* bias       = (z == 0) ? qb : (z == 1) ? kb : vb;

    int tid = threadIdx.x, lane = tid & 63, w = tid >> 6;
    int wr = w >> 1, wc = w & 1;
    int m0 = blockIdx.y * GBM, n0 = blockIdx.x * GBN;
    f32x4 acc[4][4];
#pragma unroll
    for (int i = 0; i < 4; ++i)
#pragma unroll
        for (int j = 0; j < 4; ++j) acc[i][j] = (f32x4)(0.0f);
    int colq = lane & 15, kg = lane >> 4;   // kg in 0..3: col-group kq = kg*8
    for (int kc = 0; kc < Hdim; kc += GBK) {
        __syncthreads();
        stage64(A, m0, As, tid, kc);
        stage64(W, n0, Ws, tid, kc);
        __syncthreads();
        bf16x8 af[4][2], bfr[4][2];
#pragma unroll
        for (int i = 0; i < 4; ++i) {
            int r = wr * 64 + i * 16 + colq;
            af[i][0] = frag64(As, r, kg);
            af[i][1] = frag64(As, r, 4 + kg);
        }
#pragma unroll
        for (int j = 0; j < 4; ++j) {
            int r = wc * 64 + j * 16 + colq;
            bfr[j][0] = frag64(Ws, r, kg);
            bfr[j][1] = frag64(Ws, r, 4 + kg);
        }
#pragma unroll
        for (int i = 0; i < 4; ++i)
#pragma unroll
            for (int j = 0; j < 4; ++j) {
                acc[i][j] = __builtin_amdgcn_mfma_f32_16x16x32_bf16(af[i][0], bfr[j][0], acc[i][j], 0, 0, 0);
                acc[i][j] = __builtin_amdgcn_mfma_f32_16x16x32_bf16(af[i][1], bfr[j][1], acc[i][j], 0, 0, 0);
            }
    }
    int rowq = (lane >> 4) * 4;
    if (z < 2) {
        unsigned short* outBF = (z == 0) ? Qbf : Kbf;
#pragma unroll
        for (int i = 0; i < 4; ++i)
#pragma unroll
            for (int r = 0; r < 4; ++r) {
                int m = m0 + wr * 64 + i * 16 + rowq + r;
#pragma unroll
                for (int j = 0; j < 4; ++j) {
                    int n = n0 + wc * 64 + j * 16 + colq;
                    outBF[(size_t)m * Hdim + n] = f2bf(acc[i][j][r] + bias[n]);
                }
            }
    } else {
        __syncthreads();   // all frag reads done before Ct overwrites As/Ws
#pragma unroll
        for (int i = 0; i < 4; ++i)
#pragma unroll
            for (int r = 0; r < 4; ++r) {
                int ml = wr * 64 + i * 16 + rowq + r;
#pragma unroll
                for (int j = 0; j < 4; ++j) {
                    int nl = wc * 64 + j * 16 + colq;
                    Ct[nl][ml] = (__bf16)(acc[i][j][r] + bias[n0 + nl]);
                }
            }
        __syncthreads();
        int bb = m0 >> 9, l0 = m0 & 511;
#pragma unroll
        for (int it = 0; it < 8; ++it) {
            int c = tid + it * 256;
            int nl = c >> 4;
            int o8 = (c & 15) * 8;
            int n = n0 + nl;
            int hh = n >> 6, dd = n & 63;
            bf16x8 v = *(const bf16x8*)&Ct[nl][o8];
            *(bf16x8*)(VT + ((((size_t)bb * NHEAD + hh) * HD + dd) * Ldim + l0 + o8)) = v;
        }
    }
}

// ---------------- plain bf16 GEMM 128x128 BK=64: C = A@W^T + bias [relu] -> bf16 ----------------
__global__ __launch_bounds__(256)
void gemm_plain_kernel(const unsigned short* __restrict__ A,
                       const unsigned short* __restrict__ W,
                       const float* __restrict__ bias,
                       unsigned short* __restrict__ outBF, int doRelu) {
    __shared__ __align__(16) __bf16 As[128 * 64];
    __shared__ __align__(16) __bf16 Ws[128 * 64];
    int tid = threadIdx.x, lane = tid & 63, w = tid >> 6;
    int wr = w >> 1, wc = w & 1;
    int m0 = blockIdx.y * GBM, n0 = blockIdx.x * GBN;
    f32x4 acc[4][4];
#pragma unroll
    for (int i = 0; i < 4; ++i)
#pragma unroll
        for (int j = 0; j < 4; ++j) acc[i][j] = (f32x4)(0.0f);
    int colq = lane & 15, kg = lane >> 4;
    for (int kc = 0; kc < Hdim; kc += GBK) {
        __syncthreads();
        stage64(A, m0, As, tid, kc);
        stage64(W, n0, Ws, tid, kc);
        __syncthreads();
        bf16x8 af[4][2], bfr[4][2];
#pragma unroll
        for (int i = 0; i < 4; ++i) {
            int r = wr * 64 + i * 16 + colq;
            af[i][0] = frag64(As, r, kg);
            af[i][1] = frag64(As, r, 4 + kg);
        }
#pragma unroll
        for (int j = 0; j < 4; ++j) {
            int r = wc * 64 + j * 16 + colq;
            bfr[j][0] = frag64(Ws, r, kg);
            bfr[j][1] = frag64(Ws, r, 4 + kg);
        }
#pragma unroll
        for (int i = 0; i < 4; ++i)
#pragma unroll
            for (int j = 0; j < 4; ++j) {
                acc[i][j] = __builtin_amdgcn_mfma_f32_16x16x32_bf16(af[i][0], bfr[j][0], acc[i][j], 0, 0, 0);
                acc[i][j] = __builtin_amdgcn_mfma_f32_16x16x32_bf16(af[i][1], bfr[j][1], acc[i][j], 0, 0, 0);
            }
    }
    int rowq = (lane >> 4) * 4;
#pragma unroll
    for (int i = 0; i < 4; ++i)
#pragma unroll
        for (int r = 0; r < 4; ++r) {
            int m = m0 + wr * 64 + i * 16 + rowq + r;
#pragma unroll
            for (int j = 0; j < 4; ++j) {
                int n = n0 + wc * 64 + j * 16 + colq;
                float v = acc[i][j][r] + bias[n];
                if (doRelu) v = fmaxf(v, 0.0f);
                outBF[(size_t)m * Hdim + n] = f2bf(v);
            }
        }
}

// ---------------- persistent per-(b,h) attention, 12 waves, b64-aligned slim strides ----------------
#define AKS 68
#define AVS 516
#define APS 68
#define ATTN_LDS (512 * AKS * 2 + 64 * AVS * 2 + 192 * APS * 2)
__global__ __launch_bounds__(768, 1)
void attn_mfma_kernel(const unsigned short* __restrict__ Qg,
                      const unsigned short* __restrict__ Kg,
                      const unsigned short* __restrict__ VTg,
                      const float* __restrict__ gates,
                      unsigned short* __restrict__ Ob, int blk) {
    extern __shared__ __align__(16) char smem[];
    __bf16 (*Ks)[AKS]  = (__bf16 (*)[AKS])smem;
    __bf16 (*VTs)[AVS] = (__bf16 (*)[AVS])(smem + 512 * AKS * 2);
    __bf16 (*Ps)[APS]  = (__bf16 (*)[APS])(smem + 512 * AKS * 2 + 64 * AVS * 2);
    int h = blockIdx.x & 3, b = blockIdx.x >> 2;
    int tid = threadIdx.x, lane = tid & 63, w = tid >> 6;
    int colq = lane & 15, grp = lane >> 4;
    int rowq = grp * 4, kq = grp * 8;

    size_t baseK = (size_t)b * Ldim * Hdim + h * HD;
    for (int c = tid; c < 4096; c += 768) {
        int r = c >> 3, o = (c & 7) * 8;
        bf8u u;
        u.v8 = *(const bf16x8*)(Kg + baseK + (size_t)r * Hdim + o);
        *(bf16x4*)&Ks[r][o]     = u.v4[0];
        *(bf16x4*)&Ks[r][o + 4] = u.v4[1];
    }
    size_t baseV = ((size_t)b * NHEAD + h) * HD * Ldim;
    for (int c = tid; c < 4096; c += 768) {
        int d = c >> 6, k = (c & 63) * 8;
        bf8u u;
        u.v8 = *(const bf16x8*)(VTg + baseV + (size_t)d * Ldim + k);
        *(bf16x4*)&VTs[d][k]     = u.v4[0];
        *(bf16x4*)&VTs[d][k + 4] = u.v4[1];
    }
    __syncthreads();   // the ONLY barrier

    const float lscale = 0.125f * 1.44269504f;
    int gl[3], ng;
    if (w < 4)      { gl[0] = w;     gl[1] = 8 + w;  gl[2] = 28 + w; ng = 3; }
    else if (w < 8) { gl[0] = w;     gl[1] = 8 + w;  gl[2] = 16 + w; ng = 3; }
    else            { gl[0] = 8 + w; gl[1] = 16 + w; gl[2] = 0;      ng = 2; }

    for (int gi = 0; gi < ng; ++gi) {
        int g = gl[gi];
        int q0 = g * 16;
        size_t qrow = (size_t)(b * Ldim + q0 + colq) * Hdim + h * HD;
        bf16x8 afq0 = *(const bf16x8*)(Qg + qrow + kq);
        bf16x8 afq1 = *(const bf16x8*)(Qg + qrow + 32 + kq);
        float gql[4];
#pragma unroll
        for (int r = 0; r < 4; ++r)
            gql[r] = gates[((size_t)b * Ldim + q0 + rowq + r) * 2 + blk] * lscale;

        float lrun[4] = {0.0f, 0.0f, 0.0f, 0.0f};
        f32x4 accO[4];
#pragma unroll
        for (int jd = 0; jd < 4; ++jd) accO[jd] = (f32x4)(0.0f);

        int nfull = g >> 2;
        for (int kt = 0; kt <= nfull; ++kt) {
            int k0 = kt * 64;
            bool diag = (kt == nfull);
            f32x4 sv[4];
#pragma unroll
            for (int j = 0; j < 4; ++j) sv[j] = (f32x4)(0.0f);
#pragma unroll
            for (int j = 0; j < 4; ++j) {
                int kr = k0 + j * 16 + colq;
                bf8u b0, b1;
                b0.v4[0] = *(const bf16x4*)&Ks[kr][kq];
                b0.v4[1] = *(const bf16x4*)&Ks[kr][kq + 4];
                b1.v4[0] = *(const bf16x4*)&Ks[kr][32 + kq];
                b1.v4[1] = *(const bf16x4*)&Ks[kr][32 + kq + 4];
                sv[j] = __builtin_amdgcn_mfma_f32_16x16x32_bf16(afq0, b0.v8, sv[j], 0, 0, 0);
                sv[j] = __builtin_amdgcn_mfma_f32_16x16x32_bf16(afq1, b1.v8, sv[j], 0, 0, 0);
            }
            float gkv[4];
#pragma unroll
            for (int j = 0; j < 4; ++j)
                gkv[j] = gates[((size_t)b * Ldim + k0 + j * 16 + colq) * 2 + blk];
#pragma unroll
            for (int r = 0; r < 4; ++r) {
                float su = 0.0f;
                float p4[4];
                if (diag) {
                    int qg = q0 + rowq + r;
#pragma unroll
                    for (int j = 0; j < 4; ++j) {
                        float v = sv[j][r] * gql[r] * gkv[j];
                        v = (k0 + j * 16 + colq > qg) ? -1e38f : v;
                        float e = exp2f(v);
                        p4[j] = e;
                        su += e;
                    }
                } else {
#pragma unroll
                    for (int j = 0; j < 4; ++j) {
                        float e = exp2f(sv[j][r] * gql[r] * gkv[j]);
                        p4[j] = e;
                        su += e;
                    }
                }
#pragma unroll
                for (int off = 1; off < 16; off <<= 1)
                    su += __shfl_xor(su, off, 16);
                lrun[r] += su;
#pragma unroll
                for (int j = 0; j < 4; ++j)
                    Ps[w * 16 + rowq + r][j * 16 + colq] = (__bf16)p4[j];
            }
            bf8u a0, a1;
            a0.v4[0] = *(const bf16x4*)&Ps[w * 16 + colq][kq];
            a0.v4[1] = *(const bf16x4*)&Ps[w * 16 + colq][kq + 4];
            a1.v4[0] = *(const bf16x4*)&Ps[w * 16 + colq][32 + kq];
            a1.v4[1] = *(const bf16x4*)&Ps[w * 16 + colq][32 + kq + 4];
#pragma unroll
            for (int jd = 0; jd < 4; ++jd) {
                int vr = jd * 16 + colq;
                bf8u v0, v1;
                v0.v4[0] = *(const bf16x4*)&VTs[vr][k0 + kq];
                v0.v4[1] = *(const bf16x4*)&VTs[vr][k0 + kq + 4];
                v1.v4[0] = *(const bf16x4*)&VTs[vr][k0 + 32 + kq];
                v1.v4[1] = *(const bf16x4*)&VTs[vr][k0 + 32 + kq + 4];
                accO[jd] = __builtin_amdgcn_mfma_f32_16x16x32_bf16(a0.v8, v0.v8, accO[jd], 0, 0, 0);
                accO[jd] = __builtin_amdgcn_mfma_f32_16x16x32_bf16(a1.v8, v1.v8, accO[jd], 0, 0, 0);
            }
        }
#pragma unroll
        for (int r = 0; r < 4; ++r) {
            float inv = 1.0f / lrun[r];
#pragma unroll
            for (int jd = 0; jd < 4; ++jd)
                Ob[(size_t)(b * Ldim + q0 + rowq + r) * Hdim + h * HD + jd * 16 + colq] =
                    f2bf(accO[jd][r] * inv);
        }
    }
}

// ---------------- launcher ----------------
extern "C" void kernel_launch(void* const* d_in, const int* in_sizes, int n_in,
                              void* d_out, int out_size, void* d_ws, size_t ws_size,
                              hipStream_t stream) {
    const int*   seqs_data = (const int*)d_in[0];
    const float* seqs      = (const float*)d_in[1];
    const int*   position  = (const int*)d_in[2];
    const float* time_emb  = (const float*)d_in[3];
    const float* pos_table = (const float*)d_in[4];
    const float* gate_W    = (const float*)d_in[5];
    const float* gate_b    = (const float*)d_in[6];
    const float* ln_attn_g = (const float*)d_in[7];
    const float* ln_attn_b = (const float*)d_in[8];
    const float* qW        = (const float*)d_in[9];
    const float* qb        = (const float*)d_in[10];
    const float* kW        = (const float*)d_in[11];
    const float* kb        = (const float*)d_in[12];
    const float* vW        = (const float*)d_in[13];
    const float* vb        = (const float*)d_in[14];
    const float* ln_ffn_g  = (const float*)d_in[15];
    const float* ln_ffn_b  = (const float*)d_in[16];
    const float* c1W       = (const float*)d_in[17];
    const float* c1b       = (const float*)d_in[18];
    const float* c2W       = (const float*)d_in[19];
    const float* c2b       = (const float*)d_in[20];
    const float* last_g    = (const float*)d_in[21];
    const float* last_b    = (const float*)d_in[22];

    size_t BUF = (size_t)NTOK * Hdim;
    float* fws = (float*)d_ws;
    float* GATES = fws;                       // NTOK*2
    float* KEEP  = GATES + (size_t)NTOK * 2;  // NTOK
    unsigned short* bws   = (unsigned short*)(KEEP + NTOK);
    unsigned short* Tbf   = bws;
    unsigned short* QXbf  = Tbf + BUF;        // Q / x / next-Q (in place)
    unsigned short* VINbf = QXbf + BUF;
    unsigned short* HIDbf = VINbf + BUF;
    unsigned short* Qbf   = HIDbf + BUF;
    unsigned short* Kbf   = Qbf + BUF;
    unsigned short* VTbf  = Kbf + BUF;        // V^T [B][NH][HD][L]
    unsigned short* QAbf  = VTbf + BUF;
    unsigned short* Zbf   = QAbf + BUF;       // c2 GEMM output
    unsigned short* Wbf   = Zbf + BUF;
    size_t WB = (size_t)Hdim * Hdim;
    unsigned short* qWbf  = Wbf;
    unsigned short* kWbf  = Wbf + 2 * WB;
    unsigned short* vWbf  = Wbf + 4 * WB;
    unsigned short* c1Wbf = Wbf + 6 * WB;
    unsigned short* c2Wbf = Wbf + 8 * WB;

    castw_kernel<<<dim3(128, 5), 256, 0, stream>>>(qW, kW, vW, c1W, c2W, Wbf);
    prep_ln_kernel<<<NTOK / 4, 256, 0, stream>>>(seqs_data, seqs, position, time_emb,
                                                 pos_table, gate_W, gate_b,
                                                 ln_attn_g, ln_attn_b,
                                                 Tbf, QXbf, VINbf, GATES, KEEP);

    dim3 qkvgrid(Hdim / GBN, NTOK / GBM, 3);   // (2, 256, 3)
    dim3 ggrid(Hdim / GBN, NTOK / GBM);        // (2, 256)
    for (int i = 0; i < 2; ++i) {
        gemm_qkv_kernel<<<qkvgrid, 256, 0, stream>>>(QXbf, Tbf, VINbf,
                                                     qWbf + i * WB, kWbf + i * WB, vWbf + i * WB,
                                                     qb + i * Hdim, kb + i * Hdim, vb + i * Hdim,
                                                     Qbf, Kbf, VTbf);
        attn_mfma_kernel<<<Bdim * NHEAD, 768, ATTN_LDS, stream>>>(Qbf, Kbf, VTbf, GATES, QAbf, i);
        ln2_kernel<<<NTOK / 4, 256, 0, stream>>>(QXbf, QAbf,
                                                 ln_ffn_g + i * Hdim, ln_ffn_b + i * Hdim);
        gemm_plain_kernel<<<ggrid, 256, 0, stream>>>(QXbf, c1Wbf + i * WB, c1b + i * Hdim, HIDbf, 1);
        gemm_plain_kernel<<<ggrid, 256, 0, stream>>>(HIDbf, c2Wbf + i * WB, c2b + i * Hdim, Zbf, 0);
        if (i == 0) {
            lnout_kernel<<<NTOK / 4, 256, 0, stream>>>(
                Zbf, QXbf, Tbf, KEEP,
                ln_attn_g + Hdim, ln_attn_b + Hdim,
                nullptr, VINbf);
        } else {
            lnout_kernel<<<NTOK / 4, 256, 0, stream>>>(
                Zbf, QXbf, Tbf, KEEP,
                last_g, last_b,
                (float*)d_out, nullptr);
        }
    }
}